// Round 1
// baseline (4318.828 us; speedup 1.0000x reference)
//
#include <hip/hip_runtime.h>

#define E_EDGES   8192
#define D_MODEL   256
#define N_COMP    20000
#define N_IND     500
#define H_HEADS   4
#define HDIM      64
#define KSPLIT    4
#define AKT       16

// ---------------------------------------------------------------------------
// Generic tiled fp32 GEMM: C[M,N] = gather(A)[M,K] @ W[N,K]^T + bias[N]
// block = 256 threads, 64x64 output tile, 4x4 micro-tile per thread.
// LDS padded to 33 floats/row: a-reads broadcast (4 distinct banks),
// b-reads 2-way bank alias (free per m136).
// ---------------------------------------------------------------------------
__global__ __launch_bounds__(256) void gemm_bias(
    const float* __restrict__ A, const int* __restrict__ gidx,
    const float* __restrict__ W, const float* __restrict__ bias,
    float* __restrict__ C, int M, int N, int K)
{
    __shared__ float As[64][33];
    __shared__ float Ws[64][33];
    const int bm = blockIdx.x * 64, bn = blockIdx.y * 64;
    const int tid = threadIdx.x;
    const int tx = tid & 15, ty = tid >> 4;
    float acc[4][4] = {{0.f, 0.f, 0.f, 0.f}};

    for (int kc = 0; kc < K; kc += 32) {
        __syncthreads();
#pragma unroll
        for (int i = 0; i < 8; i++) {
            int flat = i * 256 + tid;
            int r = flat >> 5, k = flat & 31;
            int am = bm + r;
            int arow = (am < M) ? (gidx ? gidx[am] : am) : 0;
            As[r][k] = A[(long)arow * K + kc + k];
            Ws[r][k] = W[(long)(bn + r) * K + kc + k];
        }
        __syncthreads();
#pragma unroll
        for (int k = 0; k < 32; k++) {
            float a[4], b[4];
#pragma unroll
            for (int i = 0; i < 4; i++) a[i] = As[ty * 4 + i][k];
#pragma unroll
            for (int j = 0; j < 4; j++) b[j] = Ws[tx * 4 + j][k];
#pragma unroll
            for (int i = 0; i < 4; i++)
#pragma unroll
                for (int j = 0; j < 4; j++) acc[i][j] += a[i] * b[j];
        }
    }

    const float4 bv = *(const float4*)&bias[bn + tx * 4];
#pragma unroll
    for (int i = 0; i < 4; i++) {
        int m = bm + ty * 4 + i;
        if (m >= M) continue;
        float4 o;
        o.x = acc[i][0] + bv.x;
        o.y = acc[i][1] + bv.y;
        o.z = acc[i][2] + bv.z;
        o.w = acc[i][3] + bv.w;
        *(float4*)&C[(long)m * N + bn + tx * 4] = o;
    }
}

// ---------------------------------------------------------------------------
// Flash attention (fp32), one thread per query row, K-split over blockIdx.y.
// grid = (H*32, KSPLIT), block = 256. Writes unnormalized partial acc + (m,l).
// ---------------------------------------------------------------------------
__global__ __launch_bounds__(256) void attn_partial(
    const float* __restrict__ Q, const float* __restrict__ K,
    const float* __restrict__ V,
    float* __restrict__ accP, float* __restrict__ mP, float* __restrict__ lP)
{
    const int h   = blockIdx.x >> 5;     // 4 heads x 32 q-tiles
    const int qt  = blockIdx.x & 31;
    const int ksp = blockIdx.y;
    const int q   = qt * 256 + threadIdx.x;

    float qreg[HDIM];
    const float* qp = Q + (long)q * D_MODEL + h * HDIM;
#pragma unroll
    for (int d = 0; d < HDIM; d += 4) {
        float4 t = *(const float4*)(qp + d);
        qreg[d + 0] = t.x * 0.125f;
        qreg[d + 1] = t.y * 0.125f;
        qreg[d + 2] = t.z * 0.125f;
        qreg[d + 3] = t.w * 0.125f;
    }

    float m = -3.0e38f, l = 0.f;
    float acc[HDIM];
#pragma unroll
    for (int d = 0; d < HDIM; d++) acc[d] = 0.f;

    __shared__ float Ks[AKT][HDIM];
    __shared__ float Vs[AKT][HDIM];

    const int kspan = E_EDGES / KSPLIT;
    const int k0 = ksp * kspan;

    for (int kt = 0; kt < kspan; kt += AKT) {
        __syncthreads();
        {
            int r = threadIdx.x >> 4, c4 = threadIdx.x & 15;
            long koff = (long)(k0 + kt + r) * D_MODEL + h * HDIM + c4 * 4;
            *(float4*)&Ks[r][c4 * 4] = *(const float4*)&K[koff];
            *(float4*)&Vs[r][c4 * 4] = *(const float4*)&V[koff];
        }
        __syncthreads();

        float s[AKT];
#pragma unroll
        for (int j = 0; j < AKT; j++) {
            float p0 = 0.f, p1 = 0.f, p2 = 0.f, p3 = 0.f;
#pragma unroll
            for (int d = 0; d < HDIM; d += 4) {
                p0 += qreg[d + 0] * Ks[j][d + 0];
                p1 += qreg[d + 1] * Ks[j][d + 1];
                p2 += qreg[d + 2] * Ks[j][d + 2];
                p3 += qreg[d + 3] * Ks[j][d + 3];
            }
            s[j] = (p0 + p1) + (p2 + p3);
        }

        float tm = s[0];
#pragma unroll
        for (int j = 1; j < AKT; j++) tm = fmaxf(tm, s[j]);
        float mn = fmaxf(m, tm);
        float corr = __expf(m - mn);
        l *= corr;
#pragma unroll
        for (int d = 0; d < HDIM; d++) acc[d] *= corr;

#pragma unroll
        for (int j = 0; j < AKT; j++) {
            float p = __expf(s[j] - mn);
            l += p;
#pragma unroll
            for (int d = 0; d < HDIM; d++) acc[d] += p * Vs[j][d];
        }
        m = mn;
    }

    long base = ((long)ksp * E_EDGES + q) * D_MODEL + h * HDIM;
#pragma unroll
    for (int d = 0; d < HDIM; d += 4) {
        float4 o;
        o.x = acc[d + 0]; o.y = acc[d + 1]; o.z = acc[d + 2]; o.w = acc[d + 3];
        *(float4*)&accP[base + d] = o;
    }
    mP[(ksp * H_HEADS + h) * E_EDGES + q] = m;
    lP[(ksp * H_HEADS + h) * E_EDGES + q] = l;
}

// ---------------------------------------------------------------------------
// Merge K-split partials via log-sum-exp. grid = E, block = 256 (one col each)
// ---------------------------------------------------------------------------
__global__ __launch_bounds__(256) void attn_merge(
    const float* __restrict__ accP, const float* __restrict__ mP,
    const float* __restrict__ lP, float* __restrict__ ctx)
{
    const int e = blockIdx.x;
    const int c = threadIdx.x;
    const int h = c >> 6;

    float mmax = -3.0e38f;
#pragma unroll
    for (int s = 0; s < KSPLIT; s++)
        mmax = fmaxf(mmax, mP[(s * H_HEADS + h) * E_EDGES + e]);

    float den = 0.f, num = 0.f;
#pragma unroll
    for (int s = 0; s < KSPLIT; s++) {
        float w = __expf(mP[(s * H_HEADS + h) * E_EDGES + e] - mmax);
        den += lP[(s * H_HEADS + h) * E_EDGES + e] * w;
        num += accP[((long)s * E_EDGES + e) * D_MODEL + c] * w;
    }
    ctx[(long)e * D_MODEL + c] = num / den;
}

// ---------------------------------------------------------------------------
// Scatter attn_out rows into per-company accumulator + counts. grid=E, blk=64
// ---------------------------------------------------------------------------
__global__ __launch_bounds__(64) void scatter_add(
    const float* __restrict__ attn_out, const int* __restrict__ src,
    float* __restrict__ agg, float* __restrict__ counts)
{
    const int e = blockIdx.x;
    const int t = threadIdx.x;
    const int srow = src[e];
    float4 v = *(const float4*)&attn_out[(long)e * D_MODEL + t * 4];
    float* dst = &agg[(long)srow * D_MODEL + t * 4];
    atomicAdd(dst + 0, v.x);
    atomicAdd(dst + 1, v.y);
    atomicAdd(dst + 2, v.z);
    atomicAdd(dst + 3, v.w);
    if (t == 0) atomicAdd(&counts[srow], 1.0f);
}

// ---------------------------------------------------------------------------
// out = LayerNorm(company_h + agg/(counts+1e-6)) * gamma + beta
// one wave per row, 4 rows per block.
// ---------------------------------------------------------------------------
__global__ __launch_bounds__(256) void fuse_ln(
    const float* __restrict__ company_h, const float* __restrict__ agg,
    const float* __restrict__ counts, const float* __restrict__ gamma,
    const float* __restrict__ beta, float* __restrict__ out)
{
    const int w = threadIdx.x >> 6, lane = threadIdx.x & 63;
    const int r = blockIdx.x * 4 + w;

    const float4 ch = *(const float4*)&company_h[(long)r * D_MODEL + lane * 4];
    const float4 ag = *(const float4*)&agg[(long)r * D_MODEL + lane * 4];
    const float inv = 1.0f / (counts[r] + 1e-6f);

    float o0 = ch.x + ag.x * inv;
    float o1 = ch.y + ag.y * inv;
    float o2 = ch.z + ag.z * inv;
    float o3 = ch.w + ag.w * inv;

    float sum = o0 + o1 + o2 + o3;
    float sq  = o0 * o0 + o1 * o1 + o2 * o2 + o3 * o3;
#pragma unroll
    for (int off = 1; off < 64; off <<= 1) {
        sum += __shfl_xor(sum, off);
        sq  += __shfl_xor(sq,  off);
    }
    const float mean = sum * (1.0f / 256.0f);
    const float var  = sq * (1.0f / 256.0f) - mean * mean;
    const float rstd = rsqrtf(var + 1e-5f);

    const float4 g = *(const float4*)&gamma[lane * 4];
    const float4 b = *(const float4*)&beta[lane * 4];
    float4 o;
    o.x = (o0 - mean) * rstd * g.x + b.x;
    o.y = (o1 - mean) * rstd * g.y + b.y;
    o.z = (o2 - mean) * rstd * g.z + b.z;
    o.w = (o3 - mean) * rstd * g.w + b.w;
    *(float4*)&out[(long)r * D_MODEL + lane * 4] = o;
}

// ---------------------------------------------------------------------------
extern "C" void kernel_launch(void* const* d_in, const int* in_sizes, int n_in,
                              void* d_out, int out_size, void* d_ws, size_t ws_size,
                              hipStream_t stream)
{
    const float* company_x  = (const float*)d_in[0];
    const float* industry_x = (const float*)d_in[1];
    const int*   edge       = (const int*)d_in[2];
    const float* Wc         = (const float*)d_in[3];
    const float* bc         = (const float*)d_in[4];
    const float* Wi         = (const float*)d_in[5];
    const float* bi         = (const float*)d_in[6];
    const float* w_in       = (const float*)d_in[7];
    const float* b_in       = (const float*)d_in[8];
    const float* w_out      = (const float*)d_in[9];
    const float* b_out      = (const float*)d_in[10];
    const float* gamma      = (const float*)d_in[11];
    const float* beta       = (const float*)d_in[12];
    float* out = (float*)d_out;

    const int* src = edge;
    const int* tgt = edge + E_EDGES;

    // workspace carve (floats)
    float* wf = (float*)d_ws;
    size_t o = 0;
    float* industry_h = wf + o; o += (size_t)N_IND * D_MODEL;
    float* company_h  = wf + o; o += (size_t)N_COMP * D_MODEL;
    float* Qb         = wf + o; o += (size_t)E_EDGES * D_MODEL;
    float* Kb         = wf + o; o += (size_t)E_EDGES * D_MODEL;
    float* Vb         = wf + o; o += (size_t)E_EDGES * D_MODEL;
    float* ctx        = wf + o; o += (size_t)E_EDGES * D_MODEL;
    float* attn_out   = wf + o; o += (size_t)E_EDGES * D_MODEL;
    float* accP       = wf + o; o += (size_t)KSPLIT * E_EDGES * D_MODEL;
    float* mPb        = wf + o; o += (size_t)KSPLIT * H_HEADS * E_EDGES;
    float* lPb        = wf + o; o += (size_t)KSPLIT * H_HEADS * E_EDGES;
    float* agg        = wf + o; o += (size_t)N_COMP * D_MODEL;
    float* counts     = wf + o; o += (size_t)N_COMP;

    dim3 blk(256);

    // projections
    gemm_bias<<<dim3(8, 4), blk, 0, stream>>>(industry_x, nullptr, Wi, bi,
                                              industry_h, N_IND, D_MODEL, 128);
    gemm_bias<<<dim3(313, 4), blk, 0, stream>>>(company_x, nullptr, Wc, bc,
                                                company_h, N_COMP, D_MODEL, 256);
    // QKV with fused gather
    gemm_bias<<<dim3(32, 4), blk, 0, stream>>>(company_h, src,
                                               w_in, b_in,
                                               Qb, E_EDGES, D_MODEL, 256);
    gemm_bias<<<dim3(32, 4), blk, 0, stream>>>(industry_h, tgt,
                                               w_in + 256 * 256, b_in + 256,
                                               Kb, E_EDGES, D_MODEL, 256);
    gemm_bias<<<dim3(32, 4), blk, 0, stream>>>(industry_h, tgt,
                                               w_in + 512 * 256, b_in + 512,
                                               Vb, E_EDGES, D_MODEL, 256);

    hipMemsetAsync(agg, 0, (size_t)N_COMP * D_MODEL * sizeof(float), stream);
    hipMemsetAsync(counts, 0, (size_t)N_COMP * sizeof(float), stream);

    // flash attention (k-split) + merge
    attn_partial<<<dim3(H_HEADS * 32, KSPLIT), blk, 0, stream>>>(Qb, Kb, Vb,
                                                                 accP, mPb, lPb);
    attn_merge<<<dim3(E_EDGES), blk, 0, stream>>>(accP, mPb, lPb, ctx);

    // output projection + scatter-mean
    gemm_bias<<<dim3(32, 4), blk, 0, stream>>>(ctx, nullptr, w_out, b_out,
                                               attn_out, E_EDGES, D_MODEL, 256);
    scatter_add<<<dim3(E_EDGES), dim3(64), 0, stream>>>(attn_out, src, agg, counts);

    // residual + layernorm
    fuse_ln<<<dim3(N_COMP / 4), blk, 0, stream>>>(company_h, agg, counts,
                                                  gamma, beta, out);
}

// Round 2
// 597.324 us; speedup vs baseline: 7.2303x; 7.2303x over previous
//
#include <hip/hip_runtime.h>
#include <type_traits>

#define E_EDGES   8192
#define D_MODEL   256
#define N_COMP    20000
#define N_IND     500
#define H_HEADS   4
#define HDIM      64

typedef short  bf16x8 __attribute__((ext_vector_type(8)));
typedef float  f32x4  __attribute__((ext_vector_type(4)));

static __device__ __forceinline__ unsigned short f2bf(float v) {
    unsigned u = __builtin_bit_cast(unsigned, v);
    u = (u + 0x7FFFu + ((u >> 16) & 1u)) >> 16;
    return (unsigned short)u;
}

// ---------------------------------------------------------------------------
// Generic tiled fp32 GEMM: C[M,N] = (gather(A)[M,K] @ W[N,K]^T + bias[N])*scale
// TO = float (fp32 out) or unsigned short (bf16 out).
// ---------------------------------------------------------------------------
template <typename TO>
__global__ __launch_bounds__(256) void gemm_bias(
    const float* __restrict__ A, const int* __restrict__ gidx,
    const float* __restrict__ W, const float* __restrict__ bias,
    TO* __restrict__ C, int M, int N, int K, float scale)
{
    __shared__ float As[64][33];
    __shared__ float Ws[64][33];
    const int bm = blockIdx.x * 64, bn = blockIdx.y * 64;
    const int tid = threadIdx.x;
    const int tx = tid & 15, ty = tid >> 4;
    float acc[4][4] = {{0.f, 0.f, 0.f, 0.f}};

    for (int kc = 0; kc < K; kc += 32) {
        __syncthreads();
#pragma unroll
        for (int i = 0; i < 8; i++) {
            int flat = i * 256 + tid;
            int r = flat >> 5, k = flat & 31;
            int am = bm + r;
            int arow = (am < M) ? (gidx ? gidx[am] : am) : 0;
            As[r][k] = A[(long)arow * K + kc + k];
            Ws[r][k] = W[(long)(bn + r) * K + kc + k];
        }
        __syncthreads();
#pragma unroll
        for (int k = 0; k < 32; k++) {
            float a[4], b[4];
#pragma unroll
            for (int i = 0; i < 4; i++) a[i] = As[ty * 4 + i][k];
#pragma unroll
            for (int j = 0; j < 4; j++) b[j] = Ws[tx * 4 + j][k];
#pragma unroll
            for (int i = 0; i < 4; i++)
#pragma unroll
                for (int j = 0; j < 4; j++) acc[i][j] += a[i] * b[j];
        }
    }

    const float4 bv = *(const float4*)&bias[bn + tx * 4];
#pragma unroll
    for (int i = 0; i < 4; i++) {
        int m = bm + ty * 4 + i;
        if (m >= M) continue;
        float o0 = (acc[i][0] + bv.x) * scale;
        float o1 = (acc[i][1] + bv.y) * scale;
        float o2 = (acc[i][2] + bv.z) * scale;
        float o3 = (acc[i][3] + bv.w) * scale;
        if constexpr (std::is_same<TO, unsigned short>::value) {
            ushort4 u;
            u.x = f2bf(o0); u.y = f2bf(o1); u.z = f2bf(o2); u.w = f2bf(o3);
            *(ushort4*)&C[(long)m * N + bn + tx * 4] = u;
        } else {
            float4 o; o.x = o0; o.y = o1; o.z = o2; o.w = o3;
            *(float4*)&C[(long)m * N + bn + tx * 4] = o;
        }
    }
}

// ---------------------------------------------------------------------------
// MFMA flash attention (bf16 inputs, fp32 accum).
// grid = (E/64, H), block = 256 (4 waves). Wave w owns q rows [64qt+16w, +16).
// K_lds[key][hd] bf16 swizzled; VT_lds[hd][key] bf16 swizzled; per-wave P_lds.
// ---------------------------------------------------------------------------
#define SWZK(row) (((row) & 7) << 4)
#define SWZV(row) ((((row) & 7) << 4) ^ ((((row) >> 4) & 3) << 5))

__global__ __launch_bounds__(256) void attn_mfma(
    const unsigned short* __restrict__ Qg,
    const unsigned short* __restrict__ Kg,
    const unsigned short* __restrict__ Vg,
    float* __restrict__ ctx)
{
    __shared__ unsigned short K_lds[64 * 64];
    __shared__ unsigned short VT_lds[64 * 64];
    __shared__ unsigned short P_lds[4 * 16 * 64];

    const int qt = blockIdx.x;
    const int h  = blockIdx.y;
    const int t  = threadIdx.x;
    const int wv = t >> 6;
    const int lane = t & 63;
    const int g  = lane >> 4;      // 4 groups of 16 lanes
    const int ln = lane & 15;

    char* kbase = (char*)K_lds;
    char* vbase = (char*)VT_lds;
    char* pbase = (char*)P_lds + wv * 2048;

    // Q fragments (A-operand), held in registers for the whole kernel.
    // A layout (16x16x32): row = lane&15, k = (lane>>4)*8 + e.
    bf16x8 qf[2];
    {
        const unsigned short* qp =
            Qg + ((long)(qt * 64 + wv * 16 + ln)) * D_MODEL + h * HDIM + g * 8;
        qf[0] = *(const bf16x8*)(qp);
        qf[1] = *(const bf16x8*)(qp + 32);
    }

    f32x4 acc[4];
#pragma unroll
    for (int i = 0; i < 4; i++) acc[i] = (f32x4){0.f, 0.f, 0.f, 0.f};
    float m[4] = {-3.0e38f, -3.0e38f, -3.0e38f, -3.0e38f};
    float l[4] = {0.f, 0.f, 0.f, 0.f};

    const int key  = t >> 2;       // staging: 4 threads per key row
    const int cb   = t & 3;        // 16-elem chunk

    for (int kt = 0; kt < E_EDGES / 64; kt++) {
        __syncthreads();
        // ---- stage K (row-major, swizzled) and V (transposed, swizzled) ----
        {
            long gofs = ((long)(kt * 64 + key)) * D_MODEL + h * HDIM + cb * 16;
            bf16x8 ka = *(const bf16x8*)(Kg + gofs);
            bf16x8 kb = *(const bf16x8*)(Kg + gofs + 8);
            int kb0 = key * 128 + cb * 32;
            int sw = SWZK(key);
            *(bf16x8*)(kbase + ((kb0) ^ sw))      = ka;
            *(bf16x8*)(kbase + ((kb0 + 16) ^ sw)) = kb;

            bf16x8 va = *(const bf16x8*)(Vg + gofs);
            bf16x8 vb = *(const bf16x8*)(Vg + gofs + 8);
#pragma unroll
            for (int i = 0; i < 8; i++) {
                int hd0 = cb * 16 + i;
                int hd1 = hd0 + 8;
                *(unsigned short*)(vbase + ((hd0 * 128 + key * 2) ^ SWZV(hd0))) =
                    (unsigned short)va[i];
                *(unsigned short*)(vbase + ((hd1 * 128 + key * 2) ^ SWZV(hd1))) =
                    (unsigned short)vb[i];
            }
        }
        __syncthreads();

        // ---- S = Q K^T  (4 sub-tiles of 16 keys) ----
        f32x4 S[4];
#pragma unroll
        for (int sub = 0; sub < 4; sub++) {
            int krow = sub * 16 + ln;
            int sw = SWZK(krow);
            bf16x8 k0 = *(bf16x8*)(kbase + ((krow * 128 + g * 16) ^ sw));
            bf16x8 k1 = *(bf16x8*)(kbase + ((krow * 128 + 64 + g * 16) ^ sw));
            f32x4 s = (f32x4){0.f, 0.f, 0.f, 0.f};
            s = __builtin_amdgcn_mfma_f32_16x16x32_bf16(qf[0], k0, s, 0, 0, 0);
            s = __builtin_amdgcn_mfma_f32_16x16x32_bf16(qf[1], k1, s, 0, 0, 0);
            S[sub] = s;
        }

        // ---- online softmax (rows owned by 16-lane groups) ----
        float tm[4];
#pragma unroll
        for (int r = 0; r < 4; r++)
            tm[r] = fmaxf(fmaxf(S[0][r], S[1][r]), fmaxf(S[2][r], S[3][r]));
#pragma unroll
        for (int st = 1; st < 16; st <<= 1)
#pragma unroll
            for (int r = 0; r < 4; r++) tm[r] = fmaxf(tm[r], __shfl_xor(tm[r], st));

        float corr[4];
#pragma unroll
        for (int r = 0; r < 4; r++) {
            float mn = fmaxf(m[r], tm[r]);
            corr[r] = __expf(m[r] - mn);
            m[r] = mn;
        }

        float ps[4] = {0.f, 0.f, 0.f, 0.f};
#pragma unroll
        for (int sub = 0; sub < 4; sub++)
#pragma unroll
            for (int r = 0; r < 4; r++) {
                float p = __expf(S[sub][r] - m[r]);
                S[sub][r] = p;
                ps[r] += p;
            }
#pragma unroll
        for (int st = 1; st < 16; st <<= 1)
#pragma unroll
            for (int r = 0; r < 4; r++) ps[r] += __shfl_xor(ps[r], st);
#pragma unroll
        for (int r = 0; r < 4; r++) l[r] = l[r] * corr[r] + ps[r];
#pragma unroll
        for (int i = 0; i < 4; i++)
#pragma unroll
            for (int r = 0; r < 4; r++) acc[i][r] *= corr[r];

        // ---- P -> per-wave LDS (bf16, re-layout for A-operand) ----
#pragma unroll
        for (int sub = 0; sub < 4; sub++)
#pragma unroll
            for (int r = 0; r < 4; r++) {
                int row = g * 4 + r;
                int off = row * 128 + (ln + sub * 16) * 2;
                *(unsigned short*)(pbase + (off ^ SWZK(row))) = f2bf(S[sub][r]);
            }
        // same-wave ds_write -> ds_read: compiler inserts lgkmcnt wait

        // ---- PV ----
        bf16x8 pa[2];
#pragma unroll
        for (int kf = 0; kf < 2; kf++)
            pa[kf] = *(bf16x8*)(pbase + ((ln * 128 + kf * 64 + g * 16) ^ SWZK(ln)));
#pragma unroll
        for (int t4 = 0; t4 < 4; t4++) {
#pragma unroll
            for (int kf = 0; kf < 2; kf++) {
                int row = ln + t4 * 16;
                bf16x8 vf = *(bf16x8*)(vbase + ((row * 128 + kf * 64 + g * 16) ^ SWZV(row)));
                acc[t4] = __builtin_amdgcn_mfma_f32_16x16x32_bf16(pa[kf], vf, acc[t4], 0, 0, 0);
            }
        }
    }

    // ---- epilogue: normalize, write ctx fp32 ----
#pragma unroll
    for (int t4 = 0; t4 < 4; t4++) {
#pragma unroll
        for (int r = 0; r < 4; r++) {
            int q = qt * 64 + wv * 16 + g * 4 + r;
            ctx[(long)q * D_MODEL + h * HDIM + t4 * 16 + ln] = acc[t4][r] / l[r];
        }
    }
}

// ---------------------------------------------------------------------------
__global__ __launch_bounds__(64) void scatter_add(
    const float* __restrict__ attn_out, const int* __restrict__ src,
    float* __restrict__ agg, float* __restrict__ counts)
{
    const int e = blockIdx.x;
    const int t = threadIdx.x;
    const int srow = src[e];
    float4 v = *(const float4*)&attn_out[(long)e * D_MODEL + t * 4];
    float* dst = &agg[(long)srow * D_MODEL + t * 4];
    atomicAdd(dst + 0, v.x);
    atomicAdd(dst + 1, v.y);
    atomicAdd(dst + 2, v.z);
    atomicAdd(dst + 3, v.w);
    if (t == 0) atomicAdd(&counts[srow], 1.0f);
}

// ---------------------------------------------------------------------------
__global__ __launch_bounds__(256) void fuse_ln(
    const float* __restrict__ company_h, const float* __restrict__ agg,
    const float* __restrict__ counts, const float* __restrict__ gamma,
    const float* __restrict__ beta, float* __restrict__ out)
{
    const int w = threadIdx.x >> 6, lane = threadIdx.x & 63;
    const int r = blockIdx.x * 4 + w;

    const float4 ch = *(const float4*)&company_h[(long)r * D_MODEL + lane * 4];
    const float4 ag = *(const float4*)&agg[(long)r * D_MODEL + lane * 4];
    const float inv = 1.0f / (counts[r] + 1e-6f);

    float o0 = ch.x + ag.x * inv;
    float o1 = ch.y + ag.y * inv;
    float o2 = ch.z + ag.z * inv;
    float o3 = ch.w + ag.w * inv;

    float sum = o0 + o1 + o2 + o3;
    float sq  = o0 * o0 + o1 * o1 + o2 * o2 + o3 * o3;
#pragma unroll
    for (int off = 1; off < 64; off <<= 1) {
        sum += __shfl_xor(sum, off);
        sq  += __shfl_xor(sq,  off);
    }
    const float mean = sum * (1.0f / 256.0f);
    const float var  = sq * (1.0f / 256.0f) - mean * mean;
    const float rstd = rsqrtf(var + 1e-5f);

    const float4 g = *(const float4*)&gamma[lane * 4];
    const float4 b = *(const float4*)&beta[lane * 4];
    float4 o;
    o.x = (o0 - mean) * rstd * g.x + b.x;
    o.y = (o1 - mean) * rstd * g.y + b.y;
    o.z = (o2 - mean) * rstd * g.z + b.z;
    o.w = (o3 - mean) * rstd * g.w + b.w;
    *(float4*)&out[(long)r * D_MODEL + lane * 4] = o;
}

// ---------------------------------------------------------------------------
extern "C" void kernel_launch(void* const* d_in, const int* in_sizes, int n_in,
                              void* d_out, int out_size, void* d_ws, size_t ws_size,
                              hipStream_t stream)
{
    const float* company_x  = (const float*)d_in[0];
    const float* industry_x = (const float*)d_in[1];
    const int*   edge       = (const int*)d_in[2];
    const float* Wc         = (const float*)d_in[3];
    const float* bc         = (const float*)d_in[4];
    const float* Wi         = (const float*)d_in[5];
    const float* bi         = (const float*)d_in[6];
    const float* w_in       = (const float*)d_in[7];
    const float* b_in       = (const float*)d_in[8];
    const float* w_out      = (const float*)d_in[9];
    const float* b_out      = (const float*)d_in[10];
    const float* gamma      = (const float*)d_in[11];
    const float* beta       = (const float*)d_in[12];
    float* out = (float*)d_out;

    const int* src = edge;
    const int* tgt = edge + E_EDGES;

    float* wf = (float*)d_ws;
    size_t o = 0;
    float* industry_h = wf + o; o += (size_t)N_IND * D_MODEL;
    float* company_h  = wf + o; o += (size_t)N_COMP * D_MODEL;
    unsigned short* Qb = (unsigned short*)(wf + o); o += (size_t)E_EDGES * D_MODEL / 2;
    unsigned short* Kb = (unsigned short*)(wf + o); o += (size_t)E_EDGES * D_MODEL / 2;
    unsigned short* Vb = (unsigned short*)(wf + o); o += (size_t)E_EDGES * D_MODEL / 2;
    float* ctx        = wf + o; o += (size_t)E_EDGES * D_MODEL;
    float* attn_out   = wf + o; o += (size_t)E_EDGES * D_MODEL;
    float* agg        = wf + o; o += (size_t)N_COMP * D_MODEL;
    float* counts     = wf + o; o += (size_t)N_COMP;

    dim3 blk(256);

    // projections (fp32 compute)
    gemm_bias<float><<<dim3(8, 4), blk, 0, stream>>>(
        industry_x, nullptr, Wi, bi, industry_h, N_IND, D_MODEL, 128, 1.0f);
    gemm_bias<float><<<dim3(313, 4), blk, 0, stream>>>(
        company_x, nullptr, Wc, bc, company_h, N_COMP, D_MODEL, 256, 1.0f);

    // QKV with fused gather -> bf16 (Q pre-scaled by 1/8, exact in bf16)
    gemm_bias<unsigned short><<<dim3(32, 4), blk, 0, stream>>>(
        company_h, src, w_in, b_in, Qb, E_EDGES, D_MODEL, 256, 0.125f);
    gemm_bias<unsigned short><<<dim3(32, 4), blk, 0, stream>>>(
        industry_h, tgt, w_in + 256 * 256, b_in + 256, Kb, E_EDGES, D_MODEL, 256, 1.0f);
    gemm_bias<unsigned short><<<dim3(32, 4), blk, 0, stream>>>(
        industry_h, tgt, w_in + 512 * 256, b_in + 512, Vb, E_EDGES, D_MODEL, 256, 1.0f);

    hipMemsetAsync(agg, 0, (size_t)N_COMP * D_MODEL * sizeof(float), stream);
    hipMemsetAsync(counts, 0, (size_t)N_COMP * sizeof(float), stream);

    // MFMA flash attention
    attn_mfma<<<dim3(E_EDGES / 64, H_HEADS), blk, 0, stream>>>(Qb, Kb, Vb, ctx);

    // output projection + scatter-mean
    gemm_bias<float><<<dim3(32, 4), blk, 0, stream>>>(
        ctx, nullptr, w_out, b_out, attn_out, E_EDGES, D_MODEL, 256, 1.0f);
    scatter_add<<<dim3(E_EDGES), dim3(64), 0, stream>>>(attn_out, src, agg, counts);

    // residual + layernorm
    fuse_ln<<<dim3(N_COMP / 4), blk, 0, stream>>>(company_h, agg, counts,
                                                  gamma, beta, out);
}

// Round 3
// 178.145 us; speedup vs baseline: 24.2434x; 3.3530x over previous
//
#include <hip/hip_runtime.h>

#define E_EDGES   8192
#define D_MODEL   256
#define N_COMP    20000
#define N_IND     500
#define NKEYS     512
#define H_HEADS   4
#define HDIM      64

typedef short  bf16x8 __attribute__((ext_vector_type(8)));
typedef float  f32x4  __attribute__((ext_vector_type(4)));

static __device__ __forceinline__ unsigned short f2bf(float v) {
    unsigned u = __builtin_bit_cast(unsigned, v);
    u = (u + 0x7FFFu + ((u >> 16) & 1u)) >> 16;
    return (unsigned short)u;
}

#define SWZ(r)  (((r) & 7) << 4)

// ---------------------------------------------------------------------------
// One-shot fp32 -> bf16 conversion of all static inputs (grid-stride by 8).
// ---------------------------------------------------------------------------
#define CN0 5120000L   /* company_x 20000x256 */
#define CN1   64000L   /* industry_x 500x128  */
#define CN2   65536L   /* Wc 256x256          */
#define CN3   32768L   /* Wi 256x128          */
#define CN4  196608L   /* w_in 768x256        */
#define CN5   65536L   /* w_out 256x256       */
#define CC1 (CN0)
#define CC2 (CC1+CN1)
#define CC3 (CC2+CN2)
#define CC4 (CC3+CN3)
#define CC5 (CC4+CN4)
#define CC6 (CC5+CN5)

__global__ __launch_bounds__(256) void cvt_all(
    const float* __restrict__ s0, const float* __restrict__ s1,
    const float* __restrict__ s2, const float* __restrict__ s3,
    const float* __restrict__ s4, const float* __restrict__ s5,
    unsigned short* __restrict__ d0, unsigned short* __restrict__ d1,
    unsigned short* __restrict__ d2, unsigned short* __restrict__ d3,
    unsigned short* __restrict__ d4, unsigned short* __restrict__ d5)
{
    long i = ((long)blockIdx.x * 256 + threadIdx.x) * 8;
    if (i >= CC6) return;
    const float* s; unsigned short* d; long off;
    if      (i < CC1) { s = s0; d = d0; off = i; }
    else if (i < CC2) { s = s1; d = d1; off = i - CC1; }
    else if (i < CC3) { s = s2; d = d2; off = i - CC2; }
    else if (i < CC4) { s = s3; d = d3; off = i - CC3; }
    else if (i < CC5) { s = s4; d = d4; off = i - CC4; }
    else              { s = s5; d = d5; off = i - CC5; }
    float4 a = *(const float4*)(s + off);
    float4 b = *(const float4*)(s + off + 4);
    bf16x8 o;
    o[0] = (short)f2bf(a.x); o[1] = (short)f2bf(a.y);
    o[2] = (short)f2bf(a.z); o[3] = (short)f2bf(a.w);
    o[4] = (short)f2bf(b.x); o[5] = (short)f2bf(b.y);
    o[6] = (short)f2bf(b.z); o[7] = (short)f2bf(b.w);
    *(bf16x8*)(d + off) = o;
}

// ---------------------------------------------------------------------------
// Edge counting (src for pooling mean, tgt for softmax multiplicity).
// ---------------------------------------------------------------------------
__global__ __launch_bounds__(256) void count_edges(
    const int* __restrict__ src, const int* __restrict__ tgt,
    float* __restrict__ csrc, float* __restrict__ ctgt)
{
    int e = blockIdx.x * 256 + threadIdx.x;
    atomicAdd(&csrc[src[e]], 1.0f);
    atomicAdd(&ctgt[tgt[e]], 1.0f);
}

__global__ __launch_bounds__(512) void make_lnm(
    const float* __restrict__ ctgt, float* __restrict__ lnm)
{
    int i = threadIdx.x;
    float c = ctgt[i];
    lnm[i] = (c > 0.f) ? logf(c) : -1e30f;
}

// ---------------------------------------------------------------------------
// bf16 MFMA GEMM, N fixed = 256: C[M,256] = gather(A)[M,K] @ W[256,K]^T + b.
// BM=64, BK=32, 4 waves; wave w owns rows [16w,16w+16) x all 256 cols.
// MODE: 0 = fp32 out, 1 = bf16 out, 2 = both, 3 = fp32 atomic scatter by sidx.
// ---------------------------------------------------------------------------
enum { OUT_F32 = 0, OUT_BF16 = 1, OUT_BOTH = 2, OUT_SCATTER = 3 };

template <int MODE>
__global__ __launch_bounds__(256) void gemm_mfma(
    const unsigned short* __restrict__ A, const int* __restrict__ gidx, int arowmax,
    const unsigned short* __restrict__ W, const float* __restrict__ bias,
    float* __restrict__ Cf, unsigned short* __restrict__ Cb,
    const int* __restrict__ sidx, int M, int K, float scale)
{
    __shared__ unsigned short As[64 * 32];
    __shared__ unsigned short Ws[256 * 32];
    char* abase = (char*)As;
    char* wbase = (char*)Ws;

    const int bm = blockIdx.x * 64;
    const int t = threadIdx.x;
    const int wv = t >> 6, lane = t & 63, g = lane >> 4, ln = lane & 15;

    f32x4 acc[16];
#pragma unroll
    for (int i = 0; i < 16; i++) acc[i] = (f32x4){0.f, 0.f, 0.f, 0.f};

    // staging coordinates (4 threads per row, 8 bf16 each)
    const int sr = t >> 2;
    const int sc = (t & 3) * 8;
    int mrow = bm + sr; if (mrow > M - 1) mrow = M - 1;
    int arow = gidx ? gidx[mrow] : mrow;
    if (arow > arowmax - 1) arow = arowmax - 1;
    const unsigned short* aptr = A + (long)arow * K + sc;
    const int awofs = (sr * 64 + sc * 2) ^ SWZ(sr);

    for (int kc = 0; kc < K; kc += 32) {
        __syncthreads();
        *(bf16x8*)(abase + awofs) = *(const bf16x8*)(aptr + kc);
#pragma unroll
        for (int p = 0; p < 4; p++) {
            int r = p * 64 + sr;
            *(bf16x8*)(wbase + ((r * 64 + sc * 2) ^ SWZ(r))) =
                *(const bf16x8*)(W + (long)r * K + kc + sc);
        }
        __syncthreads();

        const int ar = wv * 16 + ln;
        bf16x8 af = *(bf16x8*)(abase + ((ar * 64 + g * 16) ^ SWZ(ar)));
#pragma unroll
        for (int nj = 0; nj < 16; nj++) {
            int wr = nj * 16 + ln;
            bf16x8 bf = *(bf16x8*)(wbase + ((wr * 64 + g * 16) ^ SWZ(wr)));
            acc[nj] = __builtin_amdgcn_mfma_f32_16x16x32_bf16(af, bf, acc[nj], 0, 0, 0);
        }
    }

#pragma unroll
    for (int nj = 0; nj < 16; nj++) {
        int n = nj * 16 + ln;
        float bv = bias[n];
#pragma unroll
        for (int r = 0; r < 4; r++) {
            int m = bm + wv * 16 + g * 4 + r;
            if (m >= M) continue;
            float val = (acc[nj][r] + bv) * scale;
            if constexpr (MODE == OUT_SCATTER) {
                atomicAdd(&Cf[(long)sidx[m] * 256 + n], val);
            } else if constexpr (MODE == OUT_F32) {
                Cf[(long)m * 256 + n] = val;
            } else if constexpr (MODE == OUT_BF16) {
                Cb[(long)m * 256 + n] = f2bf(val);
            } else {
                Cf[(long)m * 256 + n] = val;
                Cb[(long)m * 256 + n] = f2bf(val);
            }
        }
    }
}

// ---------------------------------------------------------------------------
// MFMA attention over 512 (padded) industry keys with ln-multiplicity bias.
// grid = (E/64, H), block = 256 (4 waves, 16 q-rows each). ctx out bf16.
// ---------------------------------------------------------------------------
#define SWZK(row) (((row) & 7) << 4)
#define SWZV(row) ((((row) & 7) << 4) ^ ((((row) >> 4) & 3) << 5))

__global__ __launch_bounds__(256) void attn_mfma(
    const unsigned short* __restrict__ Qg,
    const unsigned short* __restrict__ Kg,
    const unsigned short* __restrict__ Vg,
    const float* __restrict__ lnm,
    unsigned short* __restrict__ ctx)
{
    __shared__ unsigned short K_lds[64 * 64];
    __shared__ unsigned short VT_lds[64 * 64];
    __shared__ unsigned short P_lds[4 * 16 * 64];

    const int qt = blockIdx.x;
    const int h  = blockIdx.y;
    const int t  = threadIdx.x;
    const int wv = t >> 6;
    const int lane = t & 63;
    const int g  = lane >> 4;
    const int ln = lane & 15;

    char* kbase = (char*)K_lds;
    char* vbase = (char*)VT_lds;
    char* pbase = (char*)P_lds + wv * 2048;

    bf16x8 qf[2];
    {
        const unsigned short* qp =
            Qg + ((long)(qt * 64 + wv * 16 + ln)) * D_MODEL + h * HDIM + g * 8;
        qf[0] = *(const bf16x8*)(qp);
        qf[1] = *(const bf16x8*)(qp + 32);
    }

    f32x4 acc[4];
#pragma unroll
    for (int i = 0; i < 4; i++) acc[i] = (f32x4){0.f, 0.f, 0.f, 0.f};
    float m[4] = {-1e30f, -1e30f, -1e30f, -1e30f};
    float l[4] = {0.f, 0.f, 0.f, 0.f};

    const int key = t >> 2;
    const int cb  = t & 3;

    for (int kt = 0; kt < NKEYS / 64; kt++) {
        __syncthreads();
        {
            long gofs = ((long)(kt * 64 + key)) * D_MODEL + h * HDIM + cb * 16;
            bf16x8 ka = *(const bf16x8*)(Kg + gofs);
            bf16x8 kb = *(const bf16x8*)(Kg + gofs + 8);
            int kb0 = key * 128 + cb * 32;
            int sw = SWZK(key);
            *(bf16x8*)(kbase + ((kb0) ^ sw))      = ka;
            *(bf16x8*)(kbase + ((kb0 + 16) ^ sw)) = kb;

            bf16x8 va = *(const bf16x8*)(Vg + gofs);
            bf16x8 vb = *(const bf16x8*)(Vg + gofs + 8);
#pragma unroll
            for (int i = 0; i < 8; i++) {
                int hd0 = cb * 16 + i;
                int hd1 = hd0 + 8;
                *(unsigned short*)(vbase + ((hd0 * 128 + key * 2) ^ SWZV(hd0))) =
                    (unsigned short)va[i];
                *(unsigned short*)(vbase + ((hd1 * 128 + key * 2) ^ SWZV(hd1))) =
                    (unsigned short)vb[i];
            }
        }
        __syncthreads();

        // S = Q K^T + ln(multiplicity)
        f32x4 S[4];
#pragma unroll
        for (int sub = 0; sub < 4; sub++) {
            int krow = sub * 16 + ln;
            int sw = SWZK(krow);
            bf16x8 k0 = *(bf16x8*)(kbase + ((krow * 128 + g * 16) ^ sw));
            bf16x8 k1 = *(bf16x8*)(kbase + ((krow * 128 + 64 + g * 16) ^ sw));
            f32x4 s = (f32x4){0.f, 0.f, 0.f, 0.f};
            s = __builtin_amdgcn_mfma_f32_16x16x32_bf16(qf[0], k0, s, 0, 0, 0);
            s = __builtin_amdgcn_mfma_f32_16x16x32_bf16(qf[1], k1, s, 0, 0, 0);
            float lmv = lnm[kt * 64 + sub * 16 + ln];
#pragma unroll
            for (int r = 0; r < 4; r++) s[r] += lmv;
            S[sub] = s;
        }

        // online softmax
        float tm[4];
#pragma unroll
        for (int r = 0; r < 4; r++)
            tm[r] = fmaxf(fmaxf(S[0][r], S[1][r]), fmaxf(S[2][r], S[3][r]));
#pragma unroll
        for (int st = 1; st < 16; st <<= 1)
#pragma unroll
            for (int r = 0; r < 4; r++) tm[r] = fmaxf(tm[r], __shfl_xor(tm[r], st));

        float corr[4];
#pragma unroll
        for (int r = 0; r < 4; r++) {
            float mn = fmaxf(m[r], tm[r]);
            corr[r] = __expf(m[r] - mn);
            m[r] = mn;
        }

        float ps[4] = {0.f, 0.f, 0.f, 0.f};
#pragma unroll
        for (int sub = 0; sub < 4; sub++)
#pragma unroll
            for (int r = 0; r < 4; r++) {
                float p = __expf(S[sub][r] - m[r]);
                S[sub][r] = p;
                ps[r] += p;
            }
#pragma unroll
        for (int st = 1; st < 16; st <<= 1)
#pragma unroll
            for (int r = 0; r < 4; r++) ps[r] += __shfl_xor(ps[r], st);
#pragma unroll
        for (int r = 0; r < 4; r++) l[r] = l[r] * corr[r] + ps[r];
#pragma unroll
        for (int i = 0; i < 4; i++)
#pragma unroll
            for (int r = 0; r < 4; r++) acc[i][r] *= corr[r];

        // P -> per-wave LDS (bf16, A-operand layout)
#pragma unroll
        for (int sub = 0; sub < 4; sub++)
#pragma unroll
            for (int r = 0; r < 4; r++) {
                int row = g * 4 + r;
                int off = row * 128 + (ln + sub * 16) * 2;
                *(unsigned short*)(pbase + (off ^ SWZK(row))) = f2bf(S[sub][r]);
            }

        // PV
        bf16x8 pa[2];
#pragma unroll
        for (int kf = 0; kf < 2; kf++)
            pa[kf] = *(bf16x8*)(pbase + ((ln * 128 + kf * 64 + g * 16) ^ SWZK(ln)));
#pragma unroll
        for (int t4 = 0; t4 < 4; t4++) {
#pragma unroll
            for (int kf = 0; kf < 2; kf++) {
                int row = ln + t4 * 16;
                bf16x8 vf = *(bf16x8*)(vbase + ((row * 128 + kf * 64 + g * 16) ^ SWZV(row)));
                acc[t4] = __builtin_amdgcn_mfma_f32_16x16x32_bf16(pa[kf], vf, acc[t4], 0, 0, 0);
            }
        }
    }

#pragma unroll
    for (int t4 = 0; t4 < 4; t4++) {
#pragma unroll
        for (int r = 0; r < 4; r++) {
            int q = qt * 64 + wv * 16 + g * 4 + r;
            ctx[(long)q * D_MODEL + h * HDIM + t4 * 16 + ln] = f2bf(acc[t4][r] / l[r]);
        }
    }
}

// ---------------------------------------------------------------------------
// out = LayerNorm(company_h + agg/(counts+1e-6)) * gamma + beta
// ---------------------------------------------------------------------------
__global__ __launch_bounds__(256) void fuse_ln(
    const float* __restrict__ company_h, const float* __restrict__ agg,
    const float* __restrict__ counts, const float* __restrict__ gamma,
    const float* __restrict__ beta, float* __restrict__ out)
{
    const int w = threadIdx.x >> 6, lane = threadIdx.x & 63;
    const int r = blockIdx.x * 4 + w;

    const float4 ch = *(const float4*)&company_h[(long)r * D_MODEL + lane * 4];
    const float4 ag = *(const float4*)&agg[(long)r * D_MODEL + lane * 4];
    const float inv = 1.0f / (counts[r] + 1e-6f);

    float o0 = ch.x + ag.x * inv;
    float o1 = ch.y + ag.y * inv;
    float o2 = ch.z + ag.z * inv;
    float o3 = ch.w + ag.w * inv;

    float sum = o0 + o1 + o2 + o3;
    float sq  = o0 * o0 + o1 * o1 + o2 * o2 + o3 * o3;
#pragma unroll
    for (int off = 1; off < 64; off <<= 1) {
        sum += __shfl_xor(sum, off);
        sq  += __shfl_xor(sq,  off);
    }
    const float mean = sum * (1.0f / 256.0f);
    const float var  = sq * (1.0f / 256.0f) - mean * mean;
    const float rstd = rsqrtf(var + 1e-5f);

    const float4 g = *(const float4*)&gamma[lane * 4];
    const float4 b = *(const float4*)&beta[lane * 4];
    float4 o;
    o.x = (o0 - mean) * rstd * g.x + b.x;
    o.y = (o1 - mean) * rstd * g.y + b.y;
    o.z = (o2 - mean) * rstd * g.z + b.z;
    o.w = (o3 - mean) * rstd * g.w + b.w;
    *(float4*)&out[(long)r * D_MODEL + lane * 4] = o;
}

// ---------------------------------------------------------------------------
extern "C" void kernel_launch(void* const* d_in, const int* in_sizes, int n_in,
                              void* d_out, int out_size, void* d_ws, size_t ws_size,
                              hipStream_t stream)
{
    const float* company_x  = (const float*)d_in[0];
    const float* industry_x = (const float*)d_in[1];
    const int*   edge       = (const int*)d_in[2];
    const float* Wc         = (const float*)d_in[3];
    const float* bc         = (const float*)d_in[4];
    const float* Wi         = (const float*)d_in[5];
    const float* bi         = (const float*)d_in[6];
    const float* w_in       = (const float*)d_in[7];
    const float* b_in       = (const float*)d_in[8];
    const float* w_out      = (const float*)d_in[9];
    const float* b_out      = (const float*)d_in[10];
    const float* gamma      = (const float*)d_in[11];
    const float* beta       = (const float*)d_in[12];
    float* out = (float*)d_out;

    const int* src = edge;
    const int* tgt = edge + E_EDGES;

    // workspace carve (float units)
    float* wf = (float*)d_ws;
    size_t o = 0;
    unsigned short* cx_bf  = (unsigned short*)(wf + o); o += CN0 / 2;
    unsigned short* ix_bf  = (unsigned short*)(wf + o); o += CN1 / 2;
    unsigned short* Wc_bf  = (unsigned short*)(wf + o); o += CN2 / 2;
    unsigned short* Wi_bf  = (unsigned short*)(wf + o); o += CN3 / 2;
    unsigned short* win_bf = (unsigned short*)(wf + o); o += CN4 / 2;
    unsigned short* wout_bf= (unsigned short*)(wf + o); o += CN5 / 2;
    float* company_h       = wf + o; o += (size_t)N_COMP * D_MODEL;
    unsigned short* ch_bf  = (unsigned short*)(wf + o); o += (size_t)N_COMP * D_MODEL / 2;
    unsigned short* ih_bf  = (unsigned short*)(wf + o); o += (size_t)NKEYS * D_MODEL / 2;
    unsigned short* Qb     = (unsigned short*)(wf + o); o += (size_t)E_EDGES * D_MODEL / 2;
    unsigned short* Kfull  = (unsigned short*)(wf + o); o += (size_t)NKEYS * D_MODEL / 2;
    unsigned short* Vfull  = (unsigned short*)(wf + o); o += (size_t)NKEYS * D_MODEL / 2;
    unsigned short* ctx_bf = (unsigned short*)(wf + o); o += (size_t)E_EDGES * D_MODEL / 2;
    float* agg             = wf + o; o += (size_t)N_COMP * D_MODEL;
    float* csrc            = wf + o; o += (size_t)N_COMP;
    float* ctgt            = wf + o; o += (size_t)NKEYS;
    float* lnm             = wf + o; o += (size_t)NKEYS;

    dim3 blk(256);

    // 1. convert all static fp32 inputs to bf16
    cvt_all<<<dim3((CC6 / 8 + 255) / 256), blk, 0, stream>>>(
        company_x, industry_x, Wc, Wi, w_in, w_out,
        cx_bf, ix_bf, Wc_bf, Wi_bf, win_bf, wout_bf);

    // 2. zero accumulators, count edges, build ln-multiplicity
    hipMemsetAsync(agg, 0, (size_t)N_COMP * D_MODEL * sizeof(float), stream);
    hipMemsetAsync(csrc, 0, (size_t)N_COMP * sizeof(float), stream);
    hipMemsetAsync(ctgt, 0, (size_t)NKEYS * sizeof(float), stream);
    count_edges<<<dim3(E_EDGES / 256), blk, 0, stream>>>(src, tgt, csrc, ctgt);
    make_lnm<<<dim3(1), dim3(512), 0, stream>>>(ctgt, lnm);

    // 3. projections (bf16 MFMA)
    gemm_mfma<OUT_BF16><<<dim3(NKEYS / 64), blk, 0, stream>>>(
        ix_bf, nullptr, N_IND, Wi_bf, bi, nullptr, ih_bf, nullptr,
        NKEYS, 128, 1.0f);
    gemm_mfma<OUT_BF16><<<dim3(NKEYS / 64), blk, 0, stream>>>(
        ih_bf, nullptr, NKEYS, win_bf + 256 * 256, b_in + 256, nullptr, Kfull,
        nullptr, NKEYS, 256, 1.0f);
    gemm_mfma<OUT_BF16><<<dim3(NKEYS / 64), blk, 0, stream>>>(
        ih_bf, nullptr, NKEYS, win_bf + 512 * 256, b_in + 512, nullptr, Vfull,
        nullptr, NKEYS, 256, 1.0f);
    gemm_mfma<OUT_BOTH><<<dim3((N_COMP + 63) / 64), blk, 0, stream>>>(
        cx_bf, nullptr, N_COMP, Wc_bf, bc, company_h, ch_bf, nullptr,
        N_COMP, 256, 1.0f);
    gemm_mfma<OUT_BF16><<<dim3(E_EDGES / 64), blk, 0, stream>>>(
        ch_bf, src, N_COMP, win_bf, b_in, nullptr, Qb, nullptr,
        E_EDGES, 256, 0.125f);

    // 4. attention over 512 industry keys (multiplicity-weighted softmax)
    attn_mfma<<<dim3(E_EDGES / 64, H_HEADS), blk, 0, stream>>>(
        Qb, Kfull, Vfull, lnm, ctx_bf);

    // 5. output projection fused with scatter-mean accumulation
    gemm_mfma<OUT_SCATTER><<<dim3(E_EDGES / 64), blk, 0, stream>>>(
        ctx_bf, nullptr, E_EDGES, wout_bf, b_out, agg, nullptr, src,
        E_EDGES, 256, 1.0f);

    // 6. residual + layernorm
    fuse_ln<<<dim3(N_COMP / 4), blk, 0, stream>>>(company_h, agg, csrc,
                                                  gamma, beta, out);
}

// Round 4
// 165.328 us; speedup vs baseline: 26.1228x; 1.0775x over previous
//
#include <hip/hip_runtime.h>
#include <type_traits>

#define E_EDGES   8192
#define D_MODEL   256
#define N_COMP    20000
#define N_IND     500
#define NKEYS     512
#define H_HEADS   4
#define HDIM      64

typedef short  bf16x8 __attribute__((ext_vector_type(8)));
typedef float  f32x4  __attribute__((ext_vector_type(4)));

static __device__ __forceinline__ unsigned short f2bf(float v) {
    unsigned u = __builtin_bit_cast(unsigned, v);
    u = (u + 0x7FFFu + ((u >> 16) & 1u)) >> 16;
    return (unsigned short)u;
}

#define SWZ(r)  (((r) & 7) << 4)

// ---------------------------------------------------------------------------
// fp32 -> bf16 conversion of the small static tensors (weights + industry_x).
// ---------------------------------------------------------------------------
#define SN1   64000L   /* industry_x 500x128 */
#define SN2   65536L   /* Wc 256x256         */
#define SN3   32768L   /* Wi 256x128         */
#define SN4  196608L   /* w_in 768x256       */
#define SN5   65536L   /* w_out 256x256      */
#define SC1 (SN1)
#define SC2 (SC1+SN2)
#define SC3 (SC2+SN3)
#define SC4 (SC3+SN4)
#define SC5 (SC4+SN5)

__global__ __launch_bounds__(256) void cvt_small(
    const float* __restrict__ s1, const float* __restrict__ s2,
    const float* __restrict__ s3, const float* __restrict__ s4,
    const float* __restrict__ s5,
    unsigned short* __restrict__ d1, unsigned short* __restrict__ d2,
    unsigned short* __restrict__ d3, unsigned short* __restrict__ d4,
    unsigned short* __restrict__ d5)
{
    long i = ((long)blockIdx.x * 256 + threadIdx.x) * 8;
    if (i >= SC5) return;
    const float* s; unsigned short* d; long off;
    if      (i < SC1) { s = s1; d = d1; off = i; }
    else if (i < SC2) { s = s2; d = d2; off = i - SC1; }
    else if (i < SC3) { s = s3; d = d3; off = i - SC2; }
    else if (i < SC4) { s = s4; d = d4; off = i - SC3; }
    else              { s = s5; d = d5; off = i - SC4; }
    float4 a = *(const float4*)(s + off);
    float4 b = *(const float4*)(s + off + 4);
    bf16x8 o;
    o[0] = (short)f2bf(a.x); o[1] = (short)f2bf(a.y);
    o[2] = (short)f2bf(a.z); o[3] = (short)f2bf(a.w);
    o[4] = (short)f2bf(b.x); o[5] = (short)f2bf(b.y);
    o[6] = (short)f2bf(b.z); o[7] = (short)f2bf(b.w);
    *(bf16x8*)(d + off) = o;
}

// ---------------------------------------------------------------------------
// Edge counting (src for pooling mean, tgt for softmax multiplicity).
// ---------------------------------------------------------------------------
__global__ __launch_bounds__(256) void count_edges(
    const int* __restrict__ src, const int* __restrict__ tgt,
    float* __restrict__ csrc, float* __restrict__ ctgt)
{
    int e = blockIdx.x * 256 + threadIdx.x;
    atomicAdd(&csrc[src[e]], 1.0f);
    atomicAdd(&ctgt[tgt[e]], 1.0f);
}

__global__ __launch_bounds__(512) void make_lnm(
    const float* __restrict__ ctgt, float* __restrict__ lnm)
{
    int i = threadIdx.x;
    float c = ctgt[i];
    lnm[i] = (c > 0.f) ? logf(c) : -1e30f;
}

// companies with >=1 outgoing edge -> dense list
__global__ __launch_bounds__(256) void compact_src(
    const float* __restrict__ csrc, int* __restrict__ list,
    int* __restrict__ nlist)
{
    int c = blockIdx.x * 256 + threadIdx.x;
    if (c >= N_COMP) return;
    if (csrc[c] > 0.f) {
        int i = atomicAdd(nlist, 1);
        list[i] = c;
    }
}

// ---------------------------------------------------------------------------
// bf16 MFMA GEMM, N fixed = 256: C[M,256] = gather(A)[M,K] @ W[256,K]^T + b.
// BM=64, BK=32, 4 waves. TA = float (convert to bf16 during staging) or
// unsigned short (already bf16).
// MODE: OUT_F32 -> Cf[m];  OUT_BF16 -> Cb[m];  OUT_LIST -> Cf[slist[m]].
// ---------------------------------------------------------------------------
enum { OUT_F32 = 0, OUT_BF16 = 1, OUT_LIST = 2 };

template <int MODE, typename TA>
__global__ __launch_bounds__(256) void gemm_mfma(
    const TA* __restrict__ A, const int* __restrict__ gidx, int arowmax,
    const unsigned short* __restrict__ W, const float* __restrict__ bias,
    float* __restrict__ Cf, unsigned short* __restrict__ Cb,
    const int* __restrict__ slist, int Mstatic, const int* __restrict__ Mptr,
    int K, float scale)
{
    const int M = Mptr ? *Mptr : Mstatic;
    const int bm = blockIdx.x * 64;
    if (bm >= M) return;

    __shared__ unsigned short As[64 * 32];
    __shared__ unsigned short Ws[256 * 32];
    char* abase = (char*)As;
    char* wbase = (char*)Ws;

    const int t = threadIdx.x;
    const int wv = t >> 6, lane = t & 63, g = lane >> 4, ln = lane & 15;

    f32x4 acc[16];
#pragma unroll
    for (int i = 0; i < 16; i++) acc[i] = (f32x4){0.f, 0.f, 0.f, 0.f};

    const int sr = t >> 2;
    const int sc = (t & 3) * 8;
    int mrow = bm + sr; if (mrow > M - 1) mrow = M - 1;
    int arow = gidx ? gidx[mrow] : mrow;
    if (arow > arowmax - 1) arow = arowmax - 1;
    const TA* aptr = A + (long)arow * K + sc;
    const int awofs = (sr * 64 + sc * 2) ^ SWZ(sr);

    for (int kc = 0; kc < K; kc += 32) {
        __syncthreads();
        if constexpr (std::is_same<TA, float>::value) {
            float4 a = *(const float4*)(aptr + kc);
            float4 b = *(const float4*)(aptr + kc + 4);
            bf16x8 v;
            v[0] = (short)f2bf(a.x); v[1] = (short)f2bf(a.y);
            v[2] = (short)f2bf(a.z); v[3] = (short)f2bf(a.w);
            v[4] = (short)f2bf(b.x); v[5] = (short)f2bf(b.y);
            v[6] = (short)f2bf(b.z); v[7] = (short)f2bf(b.w);
            *(bf16x8*)(abase + awofs) = v;
        } else {
            *(bf16x8*)(abase + awofs) = *(const bf16x8*)(aptr + kc);
        }
#pragma unroll
        for (int p = 0; p < 4; p++) {
            int r = p * 64 + sr;
            *(bf16x8*)(wbase + ((r * 64 + sc * 2) ^ SWZ(r))) =
                *(const bf16x8*)(W + (long)r * K + kc + sc);
        }
        __syncthreads();

        const int ar = wv * 16 + ln;
        bf16x8 af = *(bf16x8*)(abase + ((ar * 64 + g * 16) ^ SWZ(ar)));
#pragma unroll
        for (int nj = 0; nj < 16; nj++) {
            int wr = nj * 16 + ln;
            bf16x8 bf = *(bf16x8*)(wbase + ((wr * 64 + g * 16) ^ SWZ(wr)));
            acc[nj] = __builtin_amdgcn_mfma_f32_16x16x32_bf16(af, bf, acc[nj], 0, 0, 0);
        }
    }

#pragma unroll
    for (int nj = 0; nj < 16; nj++) {
        int n = nj * 16 + ln;
        float bv = bias[n];
#pragma unroll
        for (int r = 0; r < 4; r++) {
            int m = bm + wv * 16 + g * 4 + r;
            if (m >= M) continue;
            float val = (acc[nj][r] + bv) * scale;
            if constexpr (MODE == OUT_LIST) {
                Cf[(long)slist[m] * 256 + n] = val;
            } else if constexpr (MODE == OUT_F32) {
                Cf[(long)m * 256 + n] = val;
            } else {
                Cb[(long)m * 256 + n] = f2bf(val);
            }
        }
    }
}

// ---------------------------------------------------------------------------
// MFMA attention over 512 (padded) industry keys with ln-multiplicity bias.
// Queries = dense rows (distinct companies). grid = (128, H); early-exit on M.
// ---------------------------------------------------------------------------
#define SWZK(row) (((row) & 7) << 4)
#define SWZV(row) ((((row) & 7) << 4) ^ ((((row) >> 4) & 3) << 5))

__global__ __launch_bounds__(256) void attn_mfma(
    const unsigned short* __restrict__ Qg,
    const unsigned short* __restrict__ Kg,
    const unsigned short* __restrict__ Vg,
    const float* __restrict__ lnm,
    const int* __restrict__ Mptr,
    unsigned short* __restrict__ ctx)
{
    const int M = *Mptr;
    const int qt = blockIdx.x;
    if (qt * 64 >= M) return;

    __shared__ unsigned short K_lds[64 * 64];
    __shared__ unsigned short VT_lds[64 * 64];
    __shared__ unsigned short P_lds[4 * 16 * 64];

    const int h  = blockIdx.y;
    const int t  = threadIdx.x;
    const int wv = t >> 6;
    const int lane = t & 63;
    const int g  = lane >> 4;
    const int ln = lane & 15;

    char* kbase = (char*)K_lds;
    char* vbase = (char*)VT_lds;
    char* pbase = (char*)P_lds + wv * 2048;

    bf16x8 qf[2];
    {
        int qrow = qt * 64 + wv * 16 + ln;
        if (qrow > M - 1) qrow = M - 1;
        const unsigned short* qp =
            Qg + (long)qrow * D_MODEL + h * HDIM + g * 8;
        qf[0] = *(const bf16x8*)(qp);
        qf[1] = *(const bf16x8*)(qp + 32);
    }

    f32x4 acc[4];
#pragma unroll
    for (int i = 0; i < 4; i++) acc[i] = (f32x4){0.f, 0.f, 0.f, 0.f};
    float m[4] = {-1e30f, -1e30f, -1e30f, -1e30f};
    float l[4] = {0.f, 0.f, 0.f, 0.f};

    const int key = t >> 2;
    const int cb  = t & 3;

    for (int kt = 0; kt < NKEYS / 64; kt++) {
        __syncthreads();
        {
            long gofs = ((long)(kt * 64 + key)) * D_MODEL + h * HDIM + cb * 16;
            bf16x8 ka = *(const bf16x8*)(Kg + gofs);
            bf16x8 kb = *(const bf16x8*)(Kg + gofs + 8);
            int kb0 = key * 128 + cb * 32;
            int sw = SWZK(key);
            *(bf16x8*)(kbase + ((kb0) ^ sw))      = ka;
            *(bf16x8*)(kbase + ((kb0 + 16) ^ sw)) = kb;

            bf16x8 va = *(const bf16x8*)(Vg + gofs);
            bf16x8 vb = *(const bf16x8*)(Vg + gofs + 8);
#pragma unroll
            for (int i = 0; i < 8; i++) {
                int hd0 = cb * 16 + i;
                int hd1 = hd0 + 8;
                *(unsigned short*)(vbase + ((hd0 * 128 + key * 2) ^ SWZV(hd0))) =
                    (unsigned short)va[i];
                *(unsigned short*)(vbase + ((hd1 * 128 + key * 2) ^ SWZV(hd1))) =
                    (unsigned short)vb[i];
            }
        }
        __syncthreads();

        // S = Q K^T + ln(multiplicity)
        f32x4 S[4];
#pragma unroll
        for (int sub = 0; sub < 4; sub++) {
            int krow = sub * 16 + ln;
            int sw = SWZK(krow);
            bf16x8 k0 = *(bf16x8*)(kbase + ((krow * 128 + g * 16) ^ sw));
            bf16x8 k1 = *(bf16x8*)(kbase + ((krow * 128 + 64 + g * 16) ^ sw));
            f32x4 s = (f32x4){0.f, 0.f, 0.f, 0.f};
            s = __builtin_amdgcn_mfma_f32_16x16x32_bf16(qf[0], k0, s, 0, 0, 0);
            s = __builtin_amdgcn_mfma_f32_16x16x32_bf16(qf[1], k1, s, 0, 0, 0);
            float lmv = lnm[kt * 64 + sub * 16 + ln];
#pragma unroll
            for (int r = 0; r < 4; r++) s[r] += lmv;
            S[sub] = s;
        }

        // online softmax
        float tm[4];
#pragma unroll
        for (int r = 0; r < 4; r++)
            tm[r] = fmaxf(fmaxf(S[0][r], S[1][r]), fmaxf(S[2][r], S[3][r]));
#pragma unroll
        for (int st = 1; st < 16; st <<= 1)
#pragma unroll
            for (int r = 0; r < 4; r++) tm[r] = fmaxf(tm[r], __shfl_xor(tm[r], st));

        float corr[4];
#pragma unroll
        for (int r = 0; r < 4; r++) {
            float mn = fmaxf(m[r], tm[r]);
            corr[r] = __expf(m[r] - mn);
            m[r] = mn;
        }

        float ps[4] = {0.f, 0.f, 0.f, 0.f};
#pragma unroll
        for (int sub = 0; sub < 4; sub++)
#pragma unroll
            for (int r = 0; r < 4; r++) {
                float p = __expf(S[sub][r] - m[r]);
                S[sub][r] = p;
                ps[r] += p;
            }
#pragma unroll
        for (int st = 1; st < 16; st <<= 1)
#pragma unroll
            for (int r = 0; r < 4; r++) ps[r] += __shfl_xor(ps[r], st);
#pragma unroll
        for (int r = 0; r < 4; r++) l[r] = l[r] * corr[r] + ps[r];
#pragma unroll
        for (int i = 0; i < 4; i++)
#pragma unroll
            for (int r = 0; r < 4; r++) acc[i][r] *= corr[r];

        // P -> per-wave LDS (bf16, A-operand layout)
#pragma unroll
        for (int sub = 0; sub < 4; sub++)
#pragma unroll
            for (int r = 0; r < 4; r++) {
                int row = g * 4 + r;
                int off = row * 128 + (ln + sub * 16) * 2;
                *(unsigned short*)(pbase + (off ^ SWZK(row))) = f2bf(S[sub][r]);
            }

        // PV
        bf16x8 pa[2];
#pragma unroll
        for (int kf = 0; kf < 2; kf++)
            pa[kf] = *(bf16x8*)(pbase + ((ln * 128 + kf * 64 + g * 16) ^ SWZK(ln)));
#pragma unroll
        for (int t4 = 0; t4 < 4; t4++) {
#pragma unroll
            for (int kf = 0; kf < 2; kf++) {
                int row = ln + t4 * 16;
                bf16x8 vf = *(bf16x8*)(vbase + ((row * 128 + kf * 64 + g * 16) ^ SWZV(row)));
                acc[t4] = __builtin_amdgcn_mfma_f32_16x16x32_bf16(pa[kf], vf, acc[t4], 0, 0, 0);
            }
        }
    }

#pragma unroll
    for (int t4 = 0; t4 < 4; t4++) {
#pragma unroll
        for (int r = 0; r < 4; r++) {
            int q = qt * 64 + wv * 16 + g * 4 + r;
            ctx[(long)q * D_MODEL + h * HDIM + t4 * 16 + ln] = f2bf(acc[t4][r] / l[r]);
        }
    }
}

// ---------------------------------------------------------------------------
// out = LayerNorm(company_h + pooled*count/(count+1e-6)) * gamma + beta
// pooled only valid where count>0 (guarded).
// ---------------------------------------------------------------------------
__global__ __launch_bounds__(256) void fuse_ln(
    const float* __restrict__ company_h, const float* __restrict__ pooled,
    const float* __restrict__ counts, const float* __restrict__ gamma,
    const float* __restrict__ beta, float* __restrict__ out)
{
    const int w = threadIdx.x >> 6, lane = threadIdx.x & 63;
    const int r = blockIdx.x * 4 + w;

    const float4 ch = *(const float4*)&company_h[(long)r * D_MODEL + lane * 4];
    const float cnt = counts[r];
    float4 ag = {0.f, 0.f, 0.f, 0.f};
    float factor = 0.f;
    if (cnt > 0.f) {
        ag = *(const float4*)&pooled[(long)r * D_MODEL + lane * 4];
        factor = cnt / (cnt + 1e-6f);
    }

    float o0 = ch.x + ag.x * factor;
    float o1 = ch.y + ag.y * factor;
    float o2 = ch.z + ag.z * factor;
    float o3 = ch.w + ag.w * factor;

    float sum = o0 + o1 + o2 + o3;
    float sq  = o0 * o0 + o1 * o1 + o2 * o2 + o3 * o3;
#pragma unroll
    for (int off = 1; off < 64; off <<= 1) {
        sum += __shfl_xor(sum, off);
        sq  += __shfl_xor(sq,  off);
    }
    const float mean = sum * (1.0f / 256.0f);
    const float var  = sq * (1.0f / 256.0f) - mean * mean;
    const float rstd = rsqrtf(var + 1e-5f);

    const float4 g = *(const float4*)&gamma[lane * 4];
    const float4 b = *(const float4*)&beta[lane * 4];
    float4 o;
    o.x = (o0 - mean) * rstd * g.x + b.x;
    o.y = (o1 - mean) * rstd * g.y + b.y;
    o.z = (o2 - mean) * rstd * g.z + b.z;
    o.w = (o3 - mean) * rstd * g.w + b.w;
    *(float4*)&out[(long)r * D_MODEL + lane * 4] = o;
}

// ---------------------------------------------------------------------------
extern "C" void kernel_launch(void* const* d_in, const int* in_sizes, int n_in,
                              void* d_out, int out_size, void* d_ws, size_t ws_size,
                              hipStream_t stream)
{
    const float* company_x  = (const float*)d_in[0];
    const float* industry_x = (const float*)d_in[1];
    const int*   edge       = (const int*)d_in[2];
    const float* Wc         = (const float*)d_in[3];
    const float* bc         = (const float*)d_in[4];
    const float* Wi         = (const float*)d_in[5];
    const float* bi         = (const float*)d_in[6];
    const float* w_in       = (const float*)d_in[7];
    const float* b_in       = (const float*)d_in[8];
    const float* w_out      = (const float*)d_in[9];
    const float* b_out      = (const float*)d_in[10];
    const float* gamma      = (const float*)d_in[11];
    const float* beta       = (const float*)d_in[12];
    float* out = (float*)d_out;

    const int* src = edge;
    const int* tgt = edge + E_EDGES;

    // workspace carve (float units, 16B-aligned blocks)
    float* wf = (float*)d_ws;
    size_t o = 0;
    unsigned short* ix_bf   = (unsigned short*)(wf + o); o += SN1 / 2;
    unsigned short* Wc_bf   = (unsigned short*)(wf + o); o += SN2 / 2;
    unsigned short* Wi_bf   = (unsigned short*)(wf + o); o += SN3 / 2;
    unsigned short* win_bf  = (unsigned short*)(wf + o); o += SN4 / 2;
    unsigned short* wout_bf = (unsigned short*)(wf + o); o += SN5 / 2;
    float* company_h        = wf + o; o += (size_t)N_COMP * D_MODEL;
    unsigned short* ih_bf   = (unsigned short*)(wf + o); o += (size_t)NKEYS * D_MODEL / 2;
    unsigned short* Qb      = (unsigned short*)(wf + o); o += (size_t)E_EDGES * D_MODEL / 2;
    unsigned short* Kfull   = (unsigned short*)(wf + o); o += (size_t)NKEYS * D_MODEL / 2;
    unsigned short* Vfull   = (unsigned short*)(wf + o); o += (size_t)NKEYS * D_MODEL / 2;
    unsigned short* ctx_bf  = (unsigned short*)(wf + o); o += (size_t)E_EDGES * D_MODEL / 2;
    float* pooled           = wf + o; o += (size_t)N_COMP * D_MODEL;
    // contiguous zero-init region: csrc | ctgt | nlist
    float* csrc             = wf + o; o += (size_t)N_COMP;
    float* ctgt             = wf + o; o += (size_t)NKEYS;
    int*   nlist            = (int*)(wf + o); o += 4;
    float* lnm              = wf + o; o += (size_t)NKEYS;
    int*   list             = (int*)(wf + o); o += (size_t)E_EDGES;

    dim3 blk(256);

    // 1. convert small static tensors to bf16
    cvt_small<<<dim3((SC5 / 8 + 255) / 256), blk, 0, stream>>>(
        industry_x, Wc, Wi, w_in, w_out,
        ix_bf, Wc_bf, Wi_bf, win_bf, wout_bf);

    // 2. zero counters (single contiguous memset), count edges, lnm, compact
    hipMemsetAsync(csrc, 0, (N_COMP + NKEYS + 4) * sizeof(float), stream);
    count_edges<<<dim3(E_EDGES / 256), blk, 0, stream>>>(src, tgt, csrc, ctgt);
    make_lnm<<<dim3(1), dim3(512), 0, stream>>>(ctgt, lnm);
    compact_src<<<dim3((N_COMP + 255) / 256), blk, 0, stream>>>(csrc, list, nlist);

    // 3. projections (bf16 MFMA)
    gemm_mfma<OUT_BF16, unsigned short><<<dim3(NKEYS / 64), blk, 0, stream>>>(
        ix_bf, nullptr, N_IND, Wi_bf, bi, nullptr, ih_bf, nullptr,
        NKEYS, nullptr, 128, 1.0f);
    gemm_mfma<OUT_BF16, unsigned short><<<dim3(NKEYS / 64), blk, 0, stream>>>(
        ih_bf, nullptr, NKEYS, win_bf + 256 * 256, b_in + 256, nullptr, Kfull,
        nullptr, NKEYS, nullptr, 256, 1.0f);
    gemm_mfma<OUT_BF16, unsigned short><<<dim3(NKEYS / 64), blk, 0, stream>>>(
        ih_bf, nullptr, NKEYS, win_bf + 512 * 256, b_in + 512, nullptr, Vfull,
        nullptr, NKEYS, nullptr, 256, 1.0f);
    // company projection: fp32 A converted in staging, fp32 out
    gemm_mfma<OUT_F32, float><<<dim3((N_COMP + 63) / 64), blk, 0, stream>>>(
        company_x, nullptr, N_COMP, Wc_bf, bc, company_h, nullptr, nullptr,
        N_COMP, nullptr, 256, 1.0f);
    // Q projection for distinct source companies only (gather fp32 company_h)
    gemm_mfma<OUT_BF16, float><<<dim3(E_EDGES / 64), blk, 0, stream>>>(
        company_h, list, N_COMP, win_bf, b_in, nullptr, Qb, nullptr,
        0, nlist, 256, 0.125f);

    // 4. attention over 512 industry keys (multiplicity-weighted softmax)
    attn_mfma<<<dim3(E_EDGES / 64, H_HEADS), blk, 0, stream>>>(
        Qb, Kfull, Vfull, lnm, nlist, ctx_bf);

    // 5. output projection, direct store into pooled rows (no atomics)
    gemm_mfma<OUT_LIST, unsigned short><<<dim3(E_EDGES / 64), blk, 0, stream>>>(
        ctx_bf, nullptr, E_EDGES, wout_bf, b_out, pooled, nullptr, list,
        0, nlist, 256, 1.0f);

    // 6. residual + layernorm (pooled guarded by count)
    fuse_ln<<<dim3(N_COMP / 4), blk, 0, stream>>>(company_h, pooled, csrc,
                                                  gamma, beta, out);
}

// Round 5
// 159.072 us; speedup vs baseline: 27.1502x; 1.0393x over previous
//
#include <hip/hip_runtime.h>
#include <type_traits>

#define E_EDGES   8192
#define D_MODEL   256
#define N_COMP    20000
#define N_IND     500
#define NKEYS     512
#define H_HEADS   4
#define HDIM      64

typedef short  bf16x8 __attribute__((ext_vector_type(8)));
typedef float  f32x4  __attribute__((ext_vector_type(4)));

static __device__ __forceinline__ unsigned short f2bf(float v) {
    unsigned u = __builtin_bit_cast(unsigned, v);
    u = (u + 0x7FFFu + ((u >> 16) & 1u)) >> 16;
    return (unsigned short)u;
}

static __device__ __forceinline__ void cvt8(const float* __restrict__ s,
                                            unsigned short* __restrict__ d) {
    float4 a = *(const float4*)s;
    float4 b = *(const float4*)(s + 4);
    bf16x8 o;
    o[0] = (short)f2bf(a.x); o[1] = (short)f2bf(a.y);
    o[2] = (short)f2bf(a.z); o[3] = (short)f2bf(a.w);
    o[4] = (short)f2bf(b.x); o[5] = (short)f2bf(b.y);
    o[6] = (short)f2bf(b.z); o[7] = (short)f2bf(b.w);
    *(bf16x8*)d = o;
}

#define SWZ(r)  (((r) & 7) << 4)

// ---------------------------------------------------------------------------
// prep: block-range-dispatched fused preprocessing.
//   [0,32)    edge counting (csrc, ctgt)
//   [32,64)   Wc fp32 -> bf16 (natural)
//   [64,96)   w_out fp32 -> bf16 (natural)
//   [96,128)  Wc^T -> bf16          WcT[c][d] = Wc[d][c]
//   [128,144) Wi^T -> bf16          WiT[ci][d] = Wi[d][ci]
//   [144,156) composed biases: beff[e] = w_in[e]·(e<256?bc:bi) + b_in[e]
// ---------------------------------------------------------------------------
__global__ __launch_bounds__(256) void prep(
    const int* __restrict__ src, const int* __restrict__ tgt,
    const float* __restrict__ Wc, const float* __restrict__ Wi,
    const float* __restrict__ w_out, const float* __restrict__ w_in,
    const float* __restrict__ bc, const float* __restrict__ bi,
    const float* __restrict__ b_in,
    float* __restrict__ csrc, float* __restrict__ ctgt,
    unsigned short* __restrict__ Wc_bf, unsigned short* __restrict__ wout_bf,
    unsigned short* __restrict__ WcT_bf, unsigned short* __restrict__ WiT_bf,
    float* __restrict__ beff)
{
    const int bid = blockIdx.x, tid = threadIdx.x;
    if (bid < 32) {
        int e = bid * 256 + tid;
        atomicAdd(&csrc[src[e]], 1.0f);
        atomicAdd(&ctgt[tgt[e]], 1.0f);
    } else if (bid < 64) {
        long i = ((long)(bid - 32) * 256 + tid) * 8;
        cvt8(Wc + i, Wc_bf + i);
    } else if (bid < 96) {
        long i = ((long)(bid - 64) * 256 + tid) * 8;
        cvt8(w_out + i, wout_bf + i);
    } else if (bid < 128) {
        long o = ((long)(bid - 96) * 256 + tid) * 8;
        int c = (int)(o >> 8), d0 = (int)(o & 255);
        bf16x8 v;
#pragma unroll
        for (int j = 0; j < 8; j++) v[j] = (short)f2bf(Wc[(long)(d0 + j) * 256 + c]);
        *(bf16x8*)(WcT_bf + o) = v;
    } else if (bid < 144) {
        long o = ((long)(bid - 128) * 256 + tid) * 8;
        int ci = (int)(o >> 8), d0 = (int)(o & 255);
        bf16x8 v;
#pragma unroll
        for (int j = 0; j < 8; j++) v[j] = (short)f2bf(Wi[(long)(d0 + j) * 128 + ci]);
        *(bf16x8*)(WiT_bf + o) = v;
    } else {
        int gi = (bid - 144) * 256 + tid;      // [0, 3072)
        int e = gi >> 2, q = gi & 3;           // e in [0,768), quarter of row
        const float* base = (e < 256) ? bc : bi;
        const float* wr = w_in + (long)e * 256 + q * 64;
        const float* br = base + q * 64;
        float s = 0.f;
#pragma unroll
        for (int j = 0; j < 64; j += 4) {
            float4 w4 = *(const float4*)(wr + j);
            float4 b4 = *(const float4*)(br + j);
            s += w4.x * b4.x + w4.y * b4.y + w4.z * b4.z + w4.w * b4.w;
        }
        s += __shfl_xor(s, 1);
        s += __shfl_xor(s, 2);
        if (q == 0) beff[e] = s + b_in[e];
    }
}

// ---------------------------------------------------------------------------
// finalize: lnm from ctgt; compact distinct-src company list.
// ---------------------------------------------------------------------------
__global__ __launch_bounds__(256) void finalize(
    const float* __restrict__ ctgt, const float* __restrict__ csrc,
    float* __restrict__ lnm, int* __restrict__ list, int* __restrict__ nlist)
{
    int i = blockIdx.x * 256 + threadIdx.x;
    if (i < NKEYS) {
        float c = ctgt[i];
        lnm[i] = (c > 0.f) ? logf(c) : -1e30f;
    }
    if (i < N_COMP && csrc[i] > 0.f) {
        int k = atomicAdd(nlist, 1);
        list[k] = i;
    }
}

// ---------------------------------------------------------------------------
// bf16 MFMA GEMM: C[M, NJ*16] = gather(A)[M,K] @ W[NJ*16, K]^T + bias, *scale.
// BM=64, BK=32, 4 waves. TA = float (cvt in staging) or ushort (bf16).
// MODE: OUT_BF16 -> Cb dense; OUT_LIST -> Cf[slist[m]] (fp32 scatter rows).
// ---------------------------------------------------------------------------
enum { OUT_BF16 = 0, OUT_LIST = 1 };

template <int MODE, int NJ, typename TA>
__global__ __launch_bounds__(256) void gemm_mfma(
    const TA* __restrict__ A, const int* __restrict__ gidx, int arowmax,
    const unsigned short* __restrict__ W, const float* __restrict__ bias,
    float* __restrict__ Cf, unsigned short* __restrict__ Cb,
    const int* __restrict__ slist, int Mstatic, const int* __restrict__ Mptr,
    int K, float scale)
{
    const int M = Mptr ? *Mptr : Mstatic;
    const int bm = blockIdx.x * 64;
    if (bm >= M) return;

    __shared__ unsigned short As[64 * 32];
    __shared__ unsigned short Ws[NJ * 16 * 32];
    char* abase = (char*)As;
    char* wbase = (char*)Ws;

    const int t = threadIdx.x;
    const int wv = t >> 6, lane = t & 63, g = lane >> 4, ln = lane & 15;

    f32x4 acc[NJ];
#pragma unroll
    for (int i = 0; i < NJ; i++) acc[i] = (f32x4){0.f, 0.f, 0.f, 0.f};

    const int sr = t >> 2;
    const int sc = (t & 3) * 8;
    int mrow = bm + sr; if (mrow > M - 1) mrow = M - 1;
    int arow = gidx ? gidx[mrow] : mrow;
    if (arow > arowmax - 1) arow = arowmax - 1;
    const TA* aptr = A + (long)arow * K + sc;
    const int awofs = (sr * 64 + sc * 2) ^ SWZ(sr);

    for (int kc = 0; kc < K; kc += 32) {
        __syncthreads();
        if constexpr (std::is_same<TA, float>::value) {
            float4 a = *(const float4*)(aptr + kc);
            float4 b = *(const float4*)(aptr + kc + 4);
            bf16x8 v;
            v[0] = (short)f2bf(a.x); v[1] = (short)f2bf(a.y);
            v[2] = (short)f2bf(a.z); v[3] = (short)f2bf(a.w);
            v[4] = (short)f2bf(b.x); v[5] = (short)f2bf(b.y);
            v[6] = (short)f2bf(b.z); v[7] = (short)f2bf(b.w);
            *(bf16x8*)(abase + awofs) = v;
        } else {
            *(bf16x8*)(abase + awofs) = *(const bf16x8*)(aptr + kc);
        }
#pragma unroll
        for (int p = 0; p < (NJ * 16) / 64; p++) {
            int r = p * 64 + sr;
            *(bf16x8*)(wbase + ((r * 64 + sc * 2) ^ SWZ(r))) =
                *(const bf16x8*)(W + (long)r * K + kc + sc);
        }
        __syncthreads();

        const int ar = wv * 16 + ln;
        bf16x8 af = *(bf16x8*)(abase + ((ar * 64 + g * 16) ^ SWZ(ar)));
#pragma unroll
        for (int nj = 0; nj < NJ; nj++) {
            int wr = nj * 16 + ln;
            bf16x8 bf = *(bf16x8*)(wbase + ((wr * 64 + g * 16) ^ SWZ(wr)));
            acc[nj] = __builtin_amdgcn_mfma_f32_16x16x32_bf16(af, bf, acc[nj], 0, 0, 0);
        }
    }

#pragma unroll
    for (int nj = 0; nj < NJ; nj++) {
        int n = nj * 16 + ln;
        float bv = bias[n];
#pragma unroll
        for (int r = 0; r < 4; r++) {
            int m = bm + wv * 16 + g * 4 + r;
            if (m >= M) continue;
            float val = (acc[nj][r] + bv) * scale;
            if constexpr (MODE == OUT_LIST) {
                Cf[(long)slist[m] * (NJ * 16) + n] = val;
            } else {
                Cb[(long)m * (NJ * 16) + n] = f2bf(val);
            }
        }
    }
}

// ---------------------------------------------------------------------------
// MFMA attention over 512 padded industry keys, ln-multiplicity softmax bias.
// K/V stored interleaved in one [512][512] bf16 buffer (K cols 0-255, V 256+).
// grid = (128, H); early-exit vs *Mptr. ctx out bf16 stride 256.
// ---------------------------------------------------------------------------
#define SWZK(row) (((row) & 7) << 4)
#define SWZV(row) ((((row) & 7) << 4) ^ ((((row) >> 4) & 3) << 5))
#define KVS 512

__global__ __launch_bounds__(256) void attn_mfma(
    const unsigned short* __restrict__ Qg,
    const unsigned short* __restrict__ KV,
    const float* __restrict__ lnm,
    const int* __restrict__ Mptr,
    unsigned short* __restrict__ ctx)
{
    const int M = *Mptr;
    const int qt = blockIdx.x;
    if (qt * 64 >= M) return;

    __shared__ unsigned short K_lds[64 * 64];
    __shared__ unsigned short VT_lds[64 * 64];
    __shared__ unsigned short P_lds[4 * 16 * 64];

    const int h  = blockIdx.y;
    const int t  = threadIdx.x;
    const int wv = t >> 6;
    const int lane = t & 63;
    const int g  = lane >> 4;
    const int ln = lane & 15;

    char* kbase = (char*)K_lds;
    char* vbase = (char*)VT_lds;
    char* pbase = (char*)P_lds + wv * 2048;

    const unsigned short* Kg = KV;
    const unsigned short* Vg = KV + 256;

    bf16x8 qf[2];
    {
        int qrow = qt * 64 + wv * 16 + ln;
        if (qrow > M - 1) qrow = M - 1;
        const unsigned short* qp = Qg + (long)qrow * D_MODEL + h * HDIM + g * 8;
        qf[0] = *(const bf16x8*)(qp);
        qf[1] = *(const bf16x8*)(qp + 32);
    }

    f32x4 acc[4];
#pragma unroll
    for (int i = 0; i < 4; i++) acc[i] = (f32x4){0.f, 0.f, 0.f, 0.f};
    float m[4] = {-1e30f, -1e30f, -1e30f, -1e30f};
    float l[4] = {0.f, 0.f, 0.f, 0.f};

    const int key = t >> 2;
    const int cb  = t & 3;

    for (int kt = 0; kt < NKEYS / 64; kt++) {
        __syncthreads();
        {
            long gofs = (long)(kt * 64 + key) * KVS + h * HDIM + cb * 16;
            bf16x8 ka = *(const bf16x8*)(Kg + gofs);
            bf16x8 kb = *(const bf16x8*)(Kg + gofs + 8);
            int kb0 = key * 128 + cb * 32;
            int sw = SWZK(key);
            *(bf16x8*)(kbase + ((kb0) ^ sw))      = ka;
            *(bf16x8*)(kbase + ((kb0 + 16) ^ sw)) = kb;

            bf16x8 va = *(const bf16x8*)(Vg + gofs);
            bf16x8 vb = *(const bf16x8*)(Vg + gofs + 8);
#pragma unroll
            for (int i = 0; i < 8; i++) {
                int hd0 = cb * 16 + i;
                int hd1 = hd0 + 8;
                *(unsigned short*)(vbase + ((hd0 * 128 + key * 2) ^ SWZV(hd0))) =
                    (unsigned short)va[i];
                *(unsigned short*)(vbase + ((hd1 * 128 + key * 2) ^ SWZV(hd1))) =
                    (unsigned short)vb[i];
            }
        }
        __syncthreads();

        // S = Q K^T + ln(multiplicity)
        f32x4 S[4];
#pragma unroll
        for (int sub = 0; sub < 4; sub++) {
            int krow = sub * 16 + ln;
            int sw = SWZK(krow);
            bf16x8 k0 = *(bf16x8*)(kbase + ((krow * 128 + g * 16) ^ sw));
            bf16x8 k1 = *(bf16x8*)(kbase + ((krow * 128 + 64 + g * 16) ^ sw));
            f32x4 s = (f32x4){0.f, 0.f, 0.f, 0.f};
            s = __builtin_amdgcn_mfma_f32_16x16x32_bf16(qf[0], k0, s, 0, 0, 0);
            s = __builtin_amdgcn_mfma_f32_16x16x32_bf16(qf[1], k1, s, 0, 0, 0);
            float lmv = lnm[kt * 64 + sub * 16 + ln];
#pragma unroll
            for (int r = 0; r < 4; r++) s[r] += lmv;
            S[sub] = s;
        }

        // online softmax
        float tm[4];
#pragma unroll
        for (int r = 0; r < 4; r++)
            tm[r] = fmaxf(fmaxf(S[0][r], S[1][r]), fmaxf(S[2][r], S[3][r]));
#pragma unroll
        for (int st = 1; st < 16; st <<= 1)
#pragma unroll
            for (int r = 0; r < 4; r++) tm[r] = fmaxf(tm[r], __shfl_xor(tm[r], st));

        float corr[4];
#pragma unroll
        for (int r = 0; r < 4; r++) {
            float mn = fmaxf(m[r], tm[r]);
            corr[r] = __expf(m[r] - mn);
            m[r] = mn;
        }

        float ps[4] = {0.f, 0.f, 0.f, 0.f};
#pragma unroll
        for (int sub = 0; sub < 4; sub++)
#pragma unroll
            for (int r = 0; r < 4; r++) {
                float p = __expf(S[sub][r] - m[r]);
                S[sub][r] = p;
                ps[r] += p;
            }
#pragma unroll
        for (int st = 1; st < 16; st <<= 1)
#pragma unroll
            for (int r = 0; r < 4; r++) ps[r] += __shfl_xor(ps[r], st);
#pragma unroll
        for (int r = 0; r < 4; r++) l[r] = l[r] * corr[r] + ps[r];
#pragma unroll
        for (int i = 0; i < 4; i++)
#pragma unroll
            for (int r = 0; r < 4; r++) acc[i][r] *= corr[r];

        // P -> per-wave LDS (bf16, A-operand layout)
#pragma unroll
        for (int sub = 0; sub < 4; sub++)
#pragma unroll
            for (int r = 0; r < 4; r++) {
                int row = g * 4 + r;
                int off = row * 128 + (ln + sub * 16) * 2;
                *(unsigned short*)(pbase + (off ^ SWZK(row))) = f2bf(S[sub][r]);
            }

        // PV
        bf16x8 pa[2];
#pragma unroll
        for (int kf = 0; kf < 2; kf++)
            pa[kf] = *(bf16x8*)(pbase + ((ln * 128 + kf * 64 + g * 16) ^ SWZK(ln)));
#pragma unroll
        for (int t4 = 0; t4 < 4; t4++) {
#pragma unroll
            for (int kf = 0; kf < 2; kf++) {
                int row = ln + t4 * 16;
                bf16x8 vf = *(bf16x8*)(vbase + ((row * 128 + kf * 64 + g * 16) ^ SWZV(row)));
                acc[t4] = __builtin_amdgcn_mfma_f32_16x16x32_bf16(pa[kf], vf, acc[t4], 0, 0, 0);
            }
        }
    }

#pragma unroll
    for (int t4 = 0; t4 < 4; t4++) {
#pragma unroll
        for (int r = 0; r < 4; r++) {
            int q = qt * 64 + wv * 16 + g * 4 + r;
            ctx[(long)q * D_MODEL + h * HDIM + t4 * 16 + ln] = f2bf(acc[t4][r] / l[r]);
        }
    }
}

// ---------------------------------------------------------------------------
// Final: company GEMM (company_x @ Wc^T + bc) fused with residual+pooled+LN.
// BM=64, NJ=16. Row lives in one 16-lane group -> shuffle LN.
// ---------------------------------------------------------------------------
__global__ __launch_bounds__(256) void gemm_ln(
    const float* __restrict__ A, const unsigned short* __restrict__ W,
    const float* __restrict__ bias,
    const float* __restrict__ pooled, const float* __restrict__ csrc,
    const float* __restrict__ gamma, const float* __restrict__ beta,
    float* __restrict__ out, int M, int K)
{
    __shared__ unsigned short As[64 * 32];
    __shared__ unsigned short Ws[256 * 32];
    char* abase = (char*)As;
    char* wbase = (char*)Ws;

    const int bm = blockIdx.x * 64;
    const int t = threadIdx.x;
    const int wv = t >> 6, lane = t & 63, g = lane >> 4, ln = lane & 15;

    f32x4 acc[16];
#pragma unroll
    for (int i = 0; i < 16; i++) acc[i] = (f32x4){0.f, 0.f, 0.f, 0.f};

    const int sr = t >> 2;
    const int sc = (t & 3) * 8;
    int arow = bm + sr; if (arow > M - 1) arow = M - 1;
    const float* aptr = A + (long)arow * K + sc;
    const int awofs = (sr * 64 + sc * 2) ^ SWZ(sr);

    for (int kc = 0; kc < K; kc += 32) {
        __syncthreads();
        {
            float4 a = *(const float4*)(aptr + kc);
            float4 b = *(const float4*)(aptr + kc + 4);
            bf16x8 v;
            v[0] = (short)f2bf(a.x); v[1] = (short)f2bf(a.y);
            v[2] = (short)f2bf(a.z); v[3] = (short)f2bf(a.w);
            v[4] = (short)f2bf(b.x); v[5] = (short)f2bf(b.y);
            v[6] = (short)f2bf(b.z); v[7] = (short)f2bf(b.w);
            *(bf16x8*)(abase + awofs) = v;
        }
#pragma unroll
        for (int p = 0; p < 4; p++) {
            int r = p * 64 + sr;
            *(bf16x8*)(wbase + ((r * 64 + sc * 2) ^ SWZ(r))) =
                *(const bf16x8*)(W + (long)r * K + kc + sc);
        }
        __syncthreads();

        const int ar = wv * 16 + ln;
        bf16x8 af = *(bf16x8*)(abase + ((ar * 64 + g * 16) ^ SWZ(ar)));
#pragma unroll
        for (int nj = 0; nj < 16; nj++) {
            int wr = nj * 16 + ln;
            bf16x8 bf = *(bf16x8*)(wbase + ((wr * 64 + g * 16) ^ SWZ(wr)));
            acc[nj] = __builtin_amdgcn_mfma_f32_16x16x32_bf16(af, bf, acc[nj], 0, 0, 0);
        }
    }

    // epilogue: per owned row r: residual + pooled, LN via 16-lane shuffle
#pragma unroll
    for (int r = 0; r < 4; r++) {
        int R = bm + wv * 16 + g * 4 + r;
        bool valid = R < M;
        int Rc = valid ? R : 0;
        float cnt = csrc[Rc];
        float factor = (valid && cnt > 0.f) ? cnt / (cnt + 1e-6f) : 0.f;

        float v[16];
        float sum = 0.f, sq = 0.f;
#pragma unroll
        for (int nj = 0; nj < 16; nj++) {
            int n = nj * 16 + ln;
            float x = acc[nj][r] + bias[n] + factor * pooled[(long)Rc * 256 + n];
            v[nj] = x;
            sum += x;
            sq  += x * x;
        }
#pragma unroll
        for (int st = 1; st < 16; st <<= 1) {
            sum += __shfl_xor(sum, st);
            sq  += __shfl_xor(sq,  st);
        }
        float mean = sum * (1.0f / 256.0f);
        float var  = sq * (1.0f / 256.0f) - mean * mean;
        float rstd = rsqrtf(var + 1e-5f);
        if (valid) {
#pragma unroll
            for (int nj = 0; nj < 16; nj++) {
                int n = nj * 16 + ln;
                out[(long)R * 256 + n] = (v[nj] - mean) * rstd * gamma[n] + beta[n];
            }
        }
    }
}

// ---------------------------------------------------------------------------
extern "C" void kernel_launch(void* const* d_in, const int* in_sizes, int n_in,
                              void* d_out, int out_size, void* d_ws, size_t ws_size,
                              hipStream_t stream)
{
    const float* company_x  = (const float*)d_in[0];
    const float* industry_x = (const float*)d_in[1];
    const int*   edge       = (const int*)d_in[2];
    const float* Wc         = (const float*)d_in[3];
    const float* bc         = (const float*)d_in[4];
    const float* Wi         = (const float*)d_in[5];
    const float* bi         = (const float*)d_in[6];
    const float* w_in       = (const float*)d_in[7];
    const float* b_in       = (const float*)d_in[8];
    const float* w_out      = (const float*)d_in[9];
    const float* b_out      = (const float*)d_in[10];
    const float* gamma      = (const float*)d_in[11];
    const float* beta       = (const float*)d_in[12];
    float* out = (float*)d_out;

    const int* src = edge;
    const int* tgt = edge + E_EDGES;

    // workspace carve (float units)
    float* wf = (float*)d_ws;
    size_t o = 0;
    unsigned short* Wc_bf   = (unsigned short*)(wf + o); o += 32768;  // 256x256
    unsigned short* wout_bf = (unsigned short*)(wf + o); o += 32768;  // 256x256
    unsigned short* WcT_bf  = (unsigned short*)(wf + o); o += 32768;  // 256x256
    unsigned short* WiT_bf  = (unsigned short*)(wf + o); o += 16384;  // 128x256
    unsigned short* Wcq_bf  = (unsigned short*)(wf + o); o += 32768;  // 256x256
    unsigned short* kvw_bf  = (unsigned short*)(wf + o); o += 32768;  // 512x128
    unsigned short* KV_bf   = (unsigned short*)(wf + o); o += 131072; // 512x512
    unsigned short* Qb      = (unsigned short*)(wf + o); o += (size_t)E_EDGES * 128;
    unsigned short* ctx_bf  = (unsigned short*)(wf + o); o += (size_t)E_EDGES * 128;
    float* pooled           = wf + o; o += (size_t)N_COMP * D_MODEL;
    float* beff             = wf + o; o += 768;
    float* lnm              = wf + o; o += NKEYS;
    int*   list             = (int*)(wf + o); o += E_EDGES;
    // contiguous zeroed region: csrc | ctgt | nlist | zeros
    float* csrc             = wf + o; o += N_COMP;
    float* ctgt             = wf + o; o += NKEYS;
    int*   nlist            = (int*)(wf + o); o += 4;
    float* zeros            = wf + o; o += 256;

    dim3 blk(256);

    // 0. zero counters + zeros-vector (one contiguous memset)
    hipMemsetAsync(csrc, 0, (N_COMP + NKEYS + 4 + 256) * sizeof(float), stream);

    // 1. fused preprocessing (counts, weight converts/transposes, biases)
    prep<<<dim3(156), blk, 0, stream>>>(
        src, tgt, Wc, Wi, w_out, w_in, bc, bi, b_in,
        csrc, ctgt, Wc_bf, wout_bf, WcT_bf, WiT_bf, beff);

    // 2. lnm + distinct-src compaction
    finalize<<<dim3(79), blk, 0, stream>>>(ctgt, csrc, lnm, list, nlist);

    // 3. composed weights: Wcq = Wq@Wc  [256][256]; kvw = [Wk;Wv]@Wi [512][128]
    gemm_mfma<OUT_BF16, 16, float><<<dim3(4), blk, 0, stream>>>(
        w_in, nullptr, 256, WcT_bf, zeros, nullptr, Wcq_bf,
        nullptr, 256, nullptr, 256, 1.0f);
    gemm_mfma<OUT_BF16, 8, float><<<dim3(8), blk, 0, stream>>>(
        w_in + 256 * 256, nullptr, 512, WiT_bf, zeros, nullptr, kvw_bf,
        nullptr, 512, nullptr, 256, 1.0f);

    // 4. K,V direct from industry_x: KV[512][512] (K cols 0-255, V 256-511)
    gemm_mfma<OUT_BF16, 32, float><<<dim3(8), blk, 0, stream>>>(
        industry_x, nullptr, N_IND, kvw_bf, beff + 256, nullptr, KV_bf,
        nullptr, NKEYS, nullptr, 128, 1.0f);

    // 5. Q direct from company_x for distinct source companies (prescaled 1/8)
    gemm_mfma<OUT_BF16, 16, float><<<dim3(128), blk, 0, stream>>>(
        company_x, list, N_COMP, Wcq_bf, beff, nullptr, Qb,
        nullptr, 0, nlist, 256, 0.125f);

    // 6. attention over 512 industry keys (multiplicity-weighted softmax)
    attn_mfma<<<dim3(128, H_HEADS), blk, 0, stream>>>(Qb, KV_bf, lnm, nlist, ctx_bf);

    // 7. output projection, direct store into pooled rows
    gemm_mfma<OUT_LIST, 16, unsigned short><<<dim3(128), blk, 0, stream>>>(
        ctx_bf, nullptr, E_EDGES, wout_bf, b_out, pooled, nullptr,
        list, 0, nlist, 256, 1.0f);

    // 8. company GEMM + residual + pooled + LayerNorm -> out
    gemm_ln<<<dim3((N_COMP + 63) / 64), blk, 0, stream>>>(
        company_x, Wc_bf, bc, pooled, csrc, gamma, beta, out, N_COMP, 256);
}

// Round 6
// 122.675 us; speedup vs baseline: 35.2053x; 1.2967x over previous
//
#include <hip/hip_runtime.h>

#define E_EDGES   8192
#define N_COMP    20000
#define N_IND     500
#define NKEYS     512

typedef short  bf16x8 __attribute__((ext_vector_type(8)));
typedef float  f32x4  __attribute__((ext_vector_type(4)));

static __device__ __forceinline__ unsigned short f2bf(float v) {
    unsigned u = __builtin_bit_cast(unsigned, v);
    u = (u + 0x7FFFu + ((u >> 16) & 1u)) >> 16;
    return (unsigned short)u;
}

static __device__ __forceinline__ void cvt8(const float* __restrict__ s,
                                            unsigned short* __restrict__ d) {
    float4 a = *(const float4*)s;
    float4 b = *(const float4*)(s + 4);
    bf16x8 o;
    o[0] = (short)f2bf(a.x); o[1] = (short)f2bf(a.y);
    o[2] = (short)f2bf(a.z); o[3] = (short)f2bf(a.w);
    o[4] = (short)f2bf(b.x); o[5] = (short)f2bf(b.y);
    o[6] = (short)f2bf(b.z); o[7] = (short)f2bf(b.w);
    *(bf16x8*)d = o;
}

#define SWZ(r)   (((r) & 7) << 4)
#define SWZV(r)  ((((r) & 7) << 4) ^ ((((r) >> 4) & 3) << 5))

// helper: stage one bf16x8 from fp32 source into swizzled LDS
static __device__ __forceinline__ void stage_f32(const float* src, char* base,
                                                 int sr, int sc) {
    float4 a = *(const float4*)src;
    float4 b = *(const float4*)(src + 4);
    bf16x8 v;
    v[0] = (short)f2bf(a.x); v[1] = (short)f2bf(a.y);
    v[2] = (short)f2bf(a.z); v[3] = (short)f2bf(a.w);
    v[4] = (short)f2bf(b.x); v[5] = (short)f2bf(b.y);
    v[6] = (short)f2bf(b.z); v[7] = (short)f2bf(b.w);
    *(bf16x8*)(base + ((sr * 64 + sc * 2) ^ SWZ(sr))) = v;
}

// ---------------------------------------------------------------------------
// prep: block-range-dispatched preprocessing.
//  [0,32)    edge counting (csrc, ctgt)
//  [32,64)   Wc  -> bf16 (natural)
//  [64,96)   w_out -> bf16
//  [96,128)  Wc^T -> bf16
//  [128,144) Wi -> bf16 (natural)
//  [144,208) w_kv (= w_in rows 256:768) -> bf16
//  [208,220) composed biases beff[e] = w_in[e]·(e<256?bc:bi) + b_in[e]
// ---------------------------------------------------------------------------
__global__ __launch_bounds__(256) void prep(
    const int* __restrict__ src, const int* __restrict__ tgt,
    const float* __restrict__ Wc, const float* __restrict__ Wi,
    const float* __restrict__ w_out, const float* __restrict__ w_in,
    const float* __restrict__ bc, const float* __restrict__ bi,
    const float* __restrict__ b_in,
    float* __restrict__ csrc, float* __restrict__ ctgt,
    unsigned short* __restrict__ Wc_bf, unsigned short* __restrict__ wout_bf,
    unsigned short* __restrict__ WcT_bf, unsigned short* __restrict__ Wi_bf,
    unsigned short* __restrict__ wkv_bf, float* __restrict__ beff)
{
    const int bid = blockIdx.x, tid = threadIdx.x;
    if (bid < 32) {
        int e = bid * 256 + tid;
        atomicAdd(&csrc[src[e]], 1.0f);
        atomicAdd(&ctgt[tgt[e]], 1.0f);
    } else if (bid < 64) {
        long i = ((long)(bid - 32) * 256 + tid) * 8;
        cvt8(Wc + i, Wc_bf + i);
    } else if (bid < 96) {
        long i = ((long)(bid - 64) * 256 + tid) * 8;
        cvt8(w_out + i, wout_bf + i);
    } else if (bid < 128) {
        long o = ((long)(bid - 96) * 256 + tid) * 8;
        int c = (int)(o >> 8), d0 = (int)(o & 255);
        bf16x8 v;
#pragma unroll
        for (int j = 0; j < 8; j++) v[j] = (short)f2bf(Wc[(long)(d0 + j) * 256 + c]);
        *(bf16x8*)(WcT_bf + o) = v;
    } else if (bid < 144) {
        long i = ((long)(bid - 128) * 256 + tid) * 8;
        cvt8(Wi + i, Wi_bf + i);
    } else if (bid < 208) {
        long i = ((long)(bid - 144) * 256 + tid) * 8;
        cvt8(w_in + 65536 + i, wkv_bf + i);
    } else {
        int gi = (bid - 208) * 256 + tid;      // [0, 3072)
        int e = gi >> 2, q = gi & 3;
        const float* base = (e < 256) ? bc : bi;
        const float* wr = w_in + (long)e * 256 + q * 64;
        const float* br = base + q * 64;
        float s = 0.f;
#pragma unroll
        for (int j = 0; j < 64; j += 4) {
            float4 w4 = *(const float4*)(wr + j);
            float4 b4 = *(const float4*)(br + j);
            s += w4.x * b4.x + w4.y * b4.y + w4.z * b4.z + w4.w * b4.w;
        }
        s += __shfl_xor(s, 1);
        s += __shfl_xor(s, 2);
        if (q == 0) beff[e] = s + b_in[e];
    }
}

// ---------------------------------------------------------------------------
// fusedW: block-range dispatch.
//  [0,4)   Wcq = w_in[0:256] @ WcT^T              (256x256, K=256) -> bf16
//  [4,20)  KV direct: ih = bf16(industry_x@Wi^T); KV[.][colh] = ih@w_kv^T+beff
//          (rg = rows, colh = K-half/V-half; 8 row-groups x 2 halves)
//  [20,99) finalize: lnm from ctgt; compact distinct-src list
// ---------------------------------------------------------------------------
__global__ __launch_bounds__(256) void fusedW(
    const float* __restrict__ w_in, const unsigned short* __restrict__ WcT_bf,
    const float* __restrict__ industry_x, const unsigned short* __restrict__ Wi_bf,
    const unsigned short* __restrict__ wkv_bf, const float* __restrict__ beff,
    const float* __restrict__ ctgt, const float* __restrict__ csrc,
    unsigned short* __restrict__ Wcq_bf, unsigned short* __restrict__ KV_bf,
    float* __restrict__ lnm, int* __restrict__ list, int* __restrict__ nlist)
{
    const int bid = blockIdx.x;
    if (bid >= 20) {
        int i = (bid - 20) * 256 + threadIdx.x;
        if (i < NKEYS) {
            float c = ctgt[i];
            lnm[i] = (c > 0.f) ? logf(c) : -1e30f;
        }
        if (i < N_COMP && csrc[i] > 0.f) {
            int k = atomicAdd(nlist, 1);
            list[k] = i;
        }
        return;
    }

    __shared__ char lds[48 * 1024];
    const int t = threadIdx.x, wv = t >> 6, lane = t & 63, g = lane >> 4, ln = lane & 15;
    const int sr = t >> 2, sc = (t & 3) * 8;

    if (bid < 4) {
        // ---- Wcq = w_in[0:256] @ WcT^T ----
        char* ab = lds;            // 4 KB
        char* wb = lds + 4 * 1024; // 16 KB
        const int bm = bid * 64;
        f32x4 acc[16];
#pragma unroll
        for (int i = 0; i < 16; i++) acc[i] = (f32x4){0.f, 0.f, 0.f, 0.f};
        const float* aptr = w_in + (long)(bm + sr) * 256 + sc;
        for (int kc = 0; kc < 256; kc += 32) {
            __syncthreads();
            stage_f32(aptr + kc, ab, sr, sc);
#pragma unroll
            for (int p = 0; p < 4; p++) {
                int r = p * 64 + sr;
                *(bf16x8*)(wb + ((r * 64 + sc * 2) ^ SWZ(r))) =
                    *(const bf16x8*)(WcT_bf + (long)r * 256 + kc + sc);
            }
            __syncthreads();
            int ar = wv * 16 + ln;
            bf16x8 af = *(bf16x8*)(ab + ((ar * 64 + g * 16) ^ SWZ(ar)));
#pragma unroll
            for (int nj = 0; nj < 16; nj++) {
                int wr = nj * 16 + ln;
                bf16x8 bf = *(bf16x8*)(wb + ((wr * 64 + g * 16) ^ SWZ(wr)));
                acc[nj] = __builtin_amdgcn_mfma_f32_16x16x32_bf16(af, bf, acc[nj], 0, 0, 0);
            }
        }
#pragma unroll
        for (int nj = 0; nj < 16; nj++)
#pragma unroll
            for (int r = 0; r < 4; r++) {
                int m = bm + wv * 16 + g * 4 + r;
                Wcq_bf[(long)m * 256 + nj * 16 + ln] = f2bf(acc[nj][r]);
            }
    } else {
        // ---- KV direct ----
        const int rg = (bid - 4) >> 1, colh = (bid - 4) & 1;
        char* ab  = lds;             // 4 KB  (phase-1 A)
        char* wb1 = lds + 4 * 1024;  // 16 KB (phase-1 W; tail overlaps ih, ordered)
        char* ihb = lds + 16 * 1024; // 32 KB (ih [64][256] bf16 swizzled)
        char* wb2 = lds;             // 16 KB (phase-2 W)

        // phase 1: ih = industry_x @ Wi^T  (64 rows, K=128)
        f32x4 a1[16];
#pragma unroll
        for (int i = 0; i < 16; i++) a1[i] = (f32x4){0.f, 0.f, 0.f, 0.f};
        int arow = rg * 64 + sr; if (arow > N_IND - 1) arow = N_IND - 1;
        const float* aptr = industry_x + (long)arow * 128 + sc;
        for (int kc = 0; kc < 128; kc += 32) {
            __syncthreads();
            stage_f32(aptr + kc, ab, sr, sc);
#pragma unroll
            for (int p = 0; p < 4; p++) {
                int r = p * 64 + sr;
                *(bf16x8*)(wb1 + ((r * 64 + sc * 2) ^ SWZ(r))) =
                    *(const bf16x8*)(Wi_bf + (long)r * 128 + kc + sc);
            }
            __syncthreads();
            int ar = wv * 16 + ln;
            bf16x8 af = *(bf16x8*)(ab + ((ar * 64 + g * 16) ^ SWZ(ar)));
#pragma unroll
            for (int nj = 0; nj < 16; nj++) {
                int wr = nj * 16 + ln;
                bf16x8 bf = *(bf16x8*)(wb1 + ((wr * 64 + g * 16) ^ SWZ(wr)));
                a1[nj] = __builtin_amdgcn_mfma_f32_16x16x32_bf16(af, bf, a1[nj], 0, 0, 0);
            }
        }
        __syncthreads();
#pragma unroll
        for (int nj = 0; nj < 16; nj++)
#pragma unroll
            for (int r = 0; r < 4; r++) {
                int row = wv * 16 + g * 4 + r, col = nj * 16 + ln;
                *(unsigned short*)(ihb + ((row * 512 + col * 2) ^ SWZ(row))) =
                    f2bf(a1[nj][r]);
            }
        __syncthreads();

        // phase 2: KV half = ih @ w_kv[colh]^T + beff
        const unsigned short* wp = wkv_bf + (long)colh * 256 * 256;
        const float* bp = beff + 256 + colh * 256;
        f32x4 a2[16];
#pragma unroll
        for (int i = 0; i < 16; i++) a2[i] = (f32x4){0.f, 0.f, 0.f, 0.f};
        for (int kc = 0; kc < 256; kc += 32) {
            __syncthreads();
#pragma unroll
            for (int p = 0; p < 4; p++) {
                int r = p * 64 + sr;
                *(bf16x8*)(wb2 + ((r * 64 + sc * 2) ^ SWZ(r))) =
                    *(const bf16x8*)(wp + (long)r * 256 + kc + sc);
            }
            __syncthreads();
            int qr = wv * 16 + ln;
            bf16x8 af = *(bf16x8*)(ihb + ((qr * 512 + (kc + g * 8) * 2) ^ SWZ(qr)));
#pragma unroll
            for (int nj = 0; nj < 16; nj++) {
                int wr = nj * 16 + ln;
                bf16x8 bf = *(bf16x8*)(wb2 + ((wr * 64 + g * 16) ^ SWZ(wr)));
                a2[nj] = __builtin_amdgcn_mfma_f32_16x16x32_bf16(af, bf, a2[nj], 0, 0, 0);
            }
        }
#pragma unroll
        for (int nj = 0; nj < 16; nj++)
#pragma unroll
            for (int r = 0; r < 4; r++) {
                int R = rg * 64 + wv * 16 + g * 4 + r;
                int n = nj * 16 + ln;
                KV_bf[(long)R * 512 + colh * 256 + n] = f2bf(a2[nj][r] + bp[n]);
            }
    }
}

// ---------------------------------------------------------------------------
// megattn: per block of 64 listed companies:
//  phase 1: Q = gather(company_x) @ Wcq^T, prescaled 1/8, into Q_lds[64][256]
//  phase 2: 4 heads of flash attention over 512 keys (lnm bias);
//           each head's ctx overwrites its own Q columns in Q_lds
//  phase 3: out-proj ctx @ w_out^T + b_out -> pooled[list[row]]
// ---------------------------------------------------------------------------
__global__ __launch_bounds__(256) void megattn(
    const float* __restrict__ company_x,
    const unsigned short* __restrict__ Wcq,
    const float* __restrict__ beff,
    const unsigned short* __restrict__ KV,
    const float* __restrict__ lnm,
    const unsigned short* __restrict__ wout,
    const float* __restrict__ b_out,
    const int* __restrict__ list, const int* __restrict__ nlist,
    float* __restrict__ pooled)
{
    const int M = *nlist;
    const int bm = blockIdx.x * 64;
    if (bm >= M) return;

    __shared__ char lds[56 * 1024];
    char* qbase  = lds;                 // 32 KB: Q, later ctx
    char* kbase  = lds + 32 * 1024;     // 8 KB
    char* vbase  = lds + 40 * 1024;     // 8 KB
    char* wstage = lds + 32 * 1024;     // 16 KB (phases 1 & 3, overlaps K/V)
    char* astage = lds + 48 * 1024;     // 4 KB (phase 1, overlaps P)

    const int t = threadIdx.x, wv = t >> 6, lane = t & 63, g = lane >> 4, ln = lane & 15;
    char* pbase = lds + 48 * 1024 + wv * 2048;
    const int sr = t >> 2, sc = (t & 3) * 8;

    // ---- phase 1: Q ----
    {
        int mrow = bm + sr; if (mrow > M - 1) mrow = M - 1;
        const float* aptr = company_x + (long)list[mrow] * 256 + sc;
        f32x4 acc[16];
#pragma unroll
        for (int i = 0; i < 16; i++) acc[i] = (f32x4){0.f, 0.f, 0.f, 0.f};
        for (int kc = 0; kc < 256; kc += 32) {
            __syncthreads();
            stage_f32(aptr + kc, astage, sr, sc);
#pragma unroll
            for (int p = 0; p < 4; p++) {
                int r = p * 64 + sr;
                *(bf16x8*)(wstage + ((r * 64 + sc * 2) ^ SWZ(r))) =
                    *(const bf16x8*)(Wcq + (long)r * 256 + kc + sc);
            }
            __syncthreads();
            int ar = wv * 16 + ln;
            bf16x8 af = *(bf16x8*)(astage + ((ar * 64 + g * 16) ^ SWZ(ar)));
#pragma unroll
            for (int nj = 0; nj < 16; nj++) {
                int wr = nj * 16 + ln;
                bf16x8 bf = *(bf16x8*)(wstage + ((wr * 64 + g * 16) ^ SWZ(wr)));
                acc[nj] = __builtin_amdgcn_mfma_f32_16x16x32_bf16(af, bf, acc[nj], 0, 0, 0);
            }
        }
#pragma unroll
        for (int nj = 0; nj < 16; nj++)
#pragma unroll
            for (int r = 0; r < 4; r++) {
                int row = wv * 16 + g * 4 + r, col = nj * 16 + ln;
                *(unsigned short*)(qbase + ((row * 512 + col * 2) ^ SWZ(row))) =
                    f2bf((acc[nj][r] + beff[col]) * 0.125f);
            }
    }
    __syncthreads();

    // ---- phase 2: attention heads ----
    const int key = t >> 2, cb = t & 3;
    for (int h = 0; h < 4; h++) {
        const int qrow = wv * 16 + ln;
        bf16x8 qf0 = *(bf16x8*)(qbase + ((qrow * 512 + (h * 64 + g * 8) * 2) ^ SWZ(qrow)));
        bf16x8 qf1 = *(bf16x8*)(qbase + ((qrow * 512 + (h * 64 + 32 + g * 8) * 2) ^ SWZ(qrow)));

        f32x4 acc[4];
#pragma unroll
        for (int i = 0; i < 4; i++) acc[i] = (f32x4){0.f, 0.f, 0.f, 0.f};
        float mreg[4] = {-1e30f, -1e30f, -1e30f, -1e30f};
        float lreg[4] = {0.f, 0.f, 0.f, 0.f};

        for (int kt = 0; kt < 8; kt++) {
            __syncthreads();
            {
                long gofs = (long)(kt * 64 + key) * 512 + h * 64 + cb * 16;
                bf16x8 ka = *(const bf16x8*)(KV + gofs);
                bf16x8 kb = *(const bf16x8*)(KV + gofs + 8);
                int kb0 = key * 128 + cb * 32;
                int sw = SWZ(key);
                *(bf16x8*)(kbase + ((kb0) ^ sw))      = ka;
                *(bf16x8*)(kbase + ((kb0 + 16) ^ sw)) = kb;

                bf16x8 va = *(const bf16x8*)(KV + 256 + gofs);
                bf16x8 vb = *(const bf16x8*)(KV + 256 + gofs + 8);
#pragma unroll
                for (int i = 0; i < 8; i++) {
                    int hd0 = cb * 16 + i, hd1 = hd0 + 8;
                    *(unsigned short*)(vbase + ((hd0 * 128 + key * 2) ^ SWZV(hd0))) =
                        (unsigned short)va[i];
                    *(unsigned short*)(vbase + ((hd1 * 128 + key * 2) ^ SWZV(hd1))) =
                        (unsigned short)vb[i];
                }
            }
            __syncthreads();

            f32x4 S[4];
#pragma unroll
            for (int sub = 0; sub < 4; sub++) {
                int krow = sub * 16 + ln;
                int sw = SWZ(krow);
                bf16x8 k0 = *(bf16x8*)(kbase + ((krow * 128 + g * 16) ^ sw));
                bf16x8 k1 = *(bf16x8*)(kbase + ((krow * 128 + 64 + g * 16) ^ sw));
                f32x4 s = (f32x4){0.f, 0.f, 0.f, 0.f};
                s = __builtin_amdgcn_mfma_f32_16x16x32_bf16(qf0, k0, s, 0, 0, 0);
                s = __builtin_amdgcn_mfma_f32_16x16x32_bf16(qf1, k1, s, 0, 0, 0);
                float lmv = lnm[kt * 64 + sub * 16 + ln];
#pragma unroll
                for (int r = 0; r < 4; r++) s[r] += lmv;
                S[sub] = s;
            }

            float tm[4];
#pragma unroll
            for (int r = 0; r < 4; r++)
                tm[r] = fmaxf(fmaxf(S[0][r], S[1][r]), fmaxf(S[2][r], S[3][r]));
#pragma unroll
            for (int st = 1; st < 16; st <<= 1)
#pragma unroll
                for (int r = 0; r < 4; r++) tm[r] = fmaxf(tm[r], __shfl_xor(tm[r], st));

            float corr[4];
#pragma unroll
            for (int r = 0; r < 4; r++) {
                float mn = fmaxf(mreg[r], tm[r]);
                corr[r] = __expf(mreg[r] - mn);
                mreg[r] = mn;
            }

            float ps[4] = {0.f, 0.f, 0.f, 0.f};
#pragma unroll
            for (int sub = 0; sub < 4; sub++)
#pragma unroll
                for (int r = 0; r < 4; r++) {
                    float p = __expf(S[sub][r] - mreg[r]);
                    S[sub][r] = p;
                    ps[r] += p;
                }
#pragma unroll
            for (int st = 1; st < 16; st <<= 1)
#pragma unroll
                for (int r = 0; r < 4; r++) ps[r] += __shfl_xor(ps[r], st);
#pragma unroll
            for (int r = 0; r < 4; r++) lreg[r] = lreg[r] * corr[r] + ps[r];
#pragma unroll
            for (int i = 0; i < 4; i++)
#pragma unroll
                for (int r = 0; r < 4; r++) acc[i][r] *= corr[r];

#pragma unroll
            for (int sub = 0; sub < 4; sub++)
#pragma unroll
                for (int r = 0; r < 4; r++) {
                    int row = g * 4 + r;
                    int off = row * 128 + (ln + sub * 16) * 2;
                    *(unsigned short*)(pbase + (off ^ SWZ(row))) = f2bf(S[sub][r]);
                }

            bf16x8 pa[2];
#pragma unroll
            for (int kf = 0; kf < 2; kf++)
                pa[kf] = *(bf16x8*)(pbase + ((ln * 128 + kf * 64 + g * 16) ^ SWZ(ln)));
#pragma unroll
            for (int t4 = 0; t4 < 4; t4++) {
#pragma unroll
                for (int kf = 0; kf < 2; kf++) {
                    int row = ln + t4 * 16;
                    bf16x8 vf = *(bf16x8*)(vbase + ((row * 128 + kf * 64 + g * 16) ^ SWZV(row)));
                    acc[t4] = __builtin_amdgcn_mfma_f32_16x16x32_bf16(pa[kf], vf, acc[t4], 0, 0, 0);
                }
            }
        }

        // ctx of head h overwrites Q columns [h*64, h*64+64) (wave-local rows)
#pragma unroll
        for (int t4 = 0; t4 < 4; t4++)
#pragma unroll
            for (int r = 0; r < 4; r++) {
                int row = wv * 16 + g * 4 + r;
                int col = h * 64 + t4 * 16 + ln;
                *(unsigned short*)(qbase + ((row * 512 + col * 2) ^ SWZ(row))) =
                    f2bf(acc[t4][r] / lreg[r]);
            }
    }
    __syncthreads();

    // ---- phase 3: out-proj -> pooled ----
    {
        f32x4 acc[16];
#pragma unroll
        for (int i = 0; i < 16; i++) acc[i] = (f32x4){0.f, 0.f, 0.f, 0.f};
        for (int kc = 0; kc < 256; kc += 32) {
            __syncthreads();
#pragma unroll
            for (int p = 0; p < 4; p++) {
                int r = p * 64 + sr;
                *(bf16x8*)(wstage + ((r * 64 + sc * 2) ^ SWZ(r))) =
                    *(const bf16x8*)(wout + (long)r * 256 + kc + sc);
            }
            __syncthreads();
            int ar = wv * 16 + ln;
            bf16x8 af = *(bf16x8*)(qbase + ((ar * 512 + (kc + g * 8) * 2) ^ SWZ(ar)));
#pragma unroll
            for (int nj = 0; nj < 16; nj++) {
                int wr = nj * 16 + ln;
                bf16x8 bf = *(bf16x8*)(wstage + ((wr * 64 + g * 16) ^ SWZ(wr)));
                acc[nj] = __builtin_amdgcn_mfma_f32_16x16x32_bf16(af, bf, acc[nj], 0, 0, 0);
            }
        }
#pragma unroll
        for (int nj = 0; nj < 16; nj++) {
            int n = nj * 16 + ln;
            float bv = b_out[n];
#pragma unroll
            for (int r = 0; r < 4; r++) {
                int R = bm + wv * 16 + g * 4 + r;
                int Rc = (R > M - 1) ? (M - 1) : R;
                pooled[(long)list[Rc] * 256 + n] = acc[nj][r] + bv;
            }
        }
    }
}

// ---------------------------------------------------------------------------
// gemm_ln: company GEMM (company_x @ Wc^T + bc) fused residual+pooled+LN.
// ---------------------------------------------------------------------------
__global__ __launch_bounds__(256) void gemm_ln(
    const float* __restrict__ A, const unsigned short* __restrict__ W,
    const float* __restrict__ bias,
    const float* __restrict__ pooled, const float* __restrict__ csrc,
    const float* __restrict__ gamma, const float* __restrict__ beta,
    float* __restrict__ out, int M, int K)
{
    __shared__ unsigned short As[64 * 32];
    __shared__ unsigned short Ws[256 * 32];
    char* abase = (char*)As;
    char* wbase = (char*)Ws;

    const int bm = blockIdx.x * 64;
    const int t = threadIdx.x;
    const int wv = t >> 6, lane = t & 63, g = lane >> 4, ln = lane & 15;

    f32x4 acc[16];
#pragma unroll
    for (int i = 0; i < 16; i++) acc[i] = (f32x4){0.f, 0.f, 0.f, 0.f};

    const int sr = t >> 2;
    const int sc = (t & 3) * 8;
    int arow = bm + sr; if (arow > M - 1) arow = M - 1;
    const float* aptr = A + (long)arow * K + sc;

    for (int kc = 0; kc < K; kc += 32) {
        __syncthreads();
        stage_f32(aptr + kc, abase, sr, sc);
#pragma unroll
        for (int p = 0; p < 4; p++) {
            int r = p * 64 + sr;
            *(bf16x8*)(wbase + ((r * 64 + sc * 2) ^ SWZ(r))) =
                *(const bf16x8*)(W + (long)r * K + kc + sc);
        }
        __syncthreads();

        const int ar = wv * 16 + ln;
        bf16x8 af = *(bf16x8*)(abase + ((ar * 64 + g * 16) ^ SWZ(ar)));
#pragma unroll
        for (int nj = 0; nj < 16; nj++) {
            int wr = nj * 16 + ln;
            bf16x8 bf = *(bf16x8*)(wbase + ((wr * 64 + g * 16) ^ SWZ(wr)));
            acc[nj] = __builtin_amdgcn_mfma_f32_16x16x32_bf16(af, bf, acc[nj], 0, 0, 0);
        }
    }

#pragma unroll
    for (int r = 0; r < 4; r++) {
        int R = bm + wv * 16 + g * 4 + r;
        bool valid = R < M;
        int Rc = valid ? R : 0;
        float cnt = csrc[Rc];
        float factor = (valid && cnt > 0.f) ? cnt / (cnt + 1e-6f) : 0.f;

        float v[16];
        float sum = 0.f, sq = 0.f;
#pragma unroll
        for (int nj = 0; nj < 16; nj++) {
            int n = nj * 16 + ln;
            float x = acc[nj][r] + bias[n] + factor * pooled[(long)Rc * 256 + n];
            v[nj] = x;
            sum += x;
            sq  += x * x;
        }
#pragma unroll
        for (int st = 1; st < 16; st <<= 1) {
            sum += __shfl_xor(sum, st);
            sq  += __shfl_xor(sq,  st);
        }
        float mean = sum * (1.0f / 256.0f);
        float var  = sq * (1.0f / 256.0f) - mean * mean;
        float rstd = rsqrtf(var + 1e-5f);
        if (valid) {
#pragma unroll
            for (int nj = 0; nj < 16; nj++) {
                int n = nj * 16 + ln;
                out[(long)R * 256 + n] = (v[nj] - mean) * rstd * gamma[n] + beta[n];
            }
        }
    }
}

// ---------------------------------------------------------------------------
extern "C" void kernel_launch(void* const* d_in, const int* in_sizes, int n_in,
                              void* d_out, int out_size, void* d_ws, size_t ws_size,
                              hipStream_t stream)
{
    const float* company_x  = (const float*)d_in[0];
    const float* industry_x = (const float*)d_in[1];
    const int*   edge       = (const int*)d_in[2];
    const float* Wc         = (const float*)d_in[3];
    const float* bc         = (const float*)d_in[4];
    const float* Wi         = (const float*)d_in[5];
    const float* bi         = (const float*)d_in[6];
    const float* w_in       = (const float*)d_in[7];
    const float* b_in       = (const float*)d_in[8];
    const float* w_out      = (const float*)d_in[9];
    const float* b_out      = (const float*)d_in[10];
    const float* gamma      = (const float*)d_in[11];
    const float* beta       = (const float*)d_in[12];
    float* out = (float*)d_out;

    const int* src = edge;
    const int* tgt = edge + E_EDGES;

    // workspace carve (float units)
    float* wf = (float*)d_ws;
    size_t o = 0;
    unsigned short* Wc_bf   = (unsigned short*)(wf + o); o += 32768;
    unsigned short* wout_bf = (unsigned short*)(wf + o); o += 32768;
    unsigned short* WcT_bf  = (unsigned short*)(wf + o); o += 32768;
    unsigned short* Wi_bf   = (unsigned short*)(wf + o); o += 16384;
    unsigned short* wkv_bf  = (unsigned short*)(wf + o); o += 65536;
    unsigned short* Wcq_bf  = (unsigned short*)(wf + o); o += 32768;
    unsigned short* KV_bf   = (unsigned short*)(wf + o); o += 131072;
    float* pooled           = wf + o; o += (size_t)N_COMP * 256;
    float* beff             = wf + o; o += 768;
    float* lnm              = wf + o; o += NKEYS;
    int*   list             = (int*)(wf + o); o += E_EDGES;
    // contiguous zeroed region: csrc | ctgt | nlist
    float* csrc             = wf + o; o += N_COMP;
    float* ctgt             = wf + o; o += NKEYS;
    int*   nlist            = (int*)(wf + o); o += 4;

    dim3 blk(256);

    hipMemsetAsync(csrc, 0, (N_COMP + NKEYS + 4) * sizeof(float), stream);

    prep<<<dim3(220), blk, 0, stream>>>(
        src, tgt, Wc, Wi, w_out, w_in, bc, bi, b_in,
        csrc, ctgt, Wc_bf, wout_bf, WcT_bf, Wi_bf, wkv_bf, beff);

    fusedW<<<dim3(99), blk, 0, stream>>>(
        w_in, WcT_bf, industry_x, Wi_bf, wkv_bf, beff, ctgt, csrc,
        Wcq_bf, KV_bf, lnm, list, nlist);

    megattn<<<dim3(128), blk, 0, stream>>>(
        company_x, Wcq_bf, beff, KV_bf, lnm, wout_bf, b_out,
        list, nlist, pooled);

    gemm_ln<<<dim3((N_COMP + 63) / 64), blk, 0, stream>>>(
        company_x, Wc_bf, bc, pooled, csrc, gamma, beta, out, N_COMP, 256);
}